// Round 6
// baseline (3593.080 us; speedup 1.0000x reference)
//
#include <hip/hip_runtime.h>
#include <cmath>

#define DEVI static __device__ __forceinline__

constexpr int HIDn = 128, OUTn = 64;
constexpr int NCn = 50000, NDn = 50000, En = 400000;

// monotonic float->uint mapping for atomicMax on floats (handles signs)
DEVI unsigned fmap(float f) {
  int i = __float_as_int(f);
  return (i < 0) ? ~((unsigned)i) : (((unsigned)i) | 0x80000000u);
}
DEVI float fdecode(unsigned u) {
  int i = (u & 0x80000000u) ? (int)(u & 0x7fffffffu) : (int)(~u);
  return __int_as_float(i);
}

// input transform for fused A-loads: 0=plain, 1=elu(x), 2=elu(w2*a+w3*b)
template<int MODE>
DEVI float xform(const float* __restrict__ A, const float* __restrict__ A2,
                 float w2, float w3, size_t off)
{
  float x;
  if (MODE == 2) x = w2 * A[off] + w3 * A2[off];
  else           x = A[off];
  if (MODE >= 1) x = (x > 0.f) ? x : expm1f(x);
  return x;
}

// ---------------- GEMM: C[N,KO] = xform(A)[N,KI] @ W[KI,KO] + b ----------
template<int KI, int MODE>
__global__ __launch_bounds__(256)
void gemm_bias(const float* __restrict__ A, const float* __restrict__ A2,
               const float* __restrict__ wv,
               const float* __restrict__ W, const float* __restrict__ b,
               float* __restrict__ C, int N, int KO)
{
  __shared__ float At[32][68];   // A^T chunk: [k][row]
  __shared__ float Ws[32][68];   // W chunk:   [k][col]
  float w2 = 0.f, w3 = 0.f;
  if (MODE == 2) { w2 = wv[2]; w3 = wv[3]; }
  const int row0 = blockIdx.x * 64;
  const int col0 = blockIdx.y * 64;
  const int tid  = threadIdx.x;
  const int r0 = (tid >> 4) << 2;
  const int c0 = (tid & 15) << 2;
  float acc[4][4] = {{0.f, 0.f, 0.f, 0.f}};

  for (int k0 = 0; k0 < KI; k0 += 32) {
    {
      const int r  = tid >> 2;
      const int kq = (tid & 3) << 3;
      const int row = row0 + r;
      float tmp[8];
      if (row < N) {
        #pragma unroll
        for (int i = 0; i < 8; ++i)
          tmp[i] = xform<MODE>(A, A2, w2, w3, (size_t)row * KI + k0 + kq + i);
      } else {
        #pragma unroll
        for (int i = 0; i < 8; ++i) tmp[i] = 0.f;
      }
      #pragma unroll
      for (int i = 0; i < 8; ++i) At[kq + i][r] = tmp[i];
    }
    {
      const int k  = tid >> 3;
      const int cq = (tid & 7) << 3;
      const float* wp = W + (size_t)(k0 + k) * KO + col0 + cq;
      #pragma unroll
      for (int i = 0; i < 8; ++i) Ws[k][cq + i] = wp[i];
    }
    __syncthreads();
    #pragma unroll
    for (int k = 0; k < 32; ++k) {
      float av[4], wvv[4];
      #pragma unroll
      for (int i = 0; i < 4; ++i) av[i] = At[k][r0 + i];
      #pragma unroll
      for (int j = 0; j < 4; ++j) wvv[j] = Ws[k][c0 + j];
      #pragma unroll
      for (int i = 0; i < 4; ++i) {
        #pragma unroll
        for (int j = 0; j < 4; ++j) acc[i][j] += av[i] * wvv[j];
      }
    }
    __syncthreads();
  }

  #pragma unroll
  for (int i = 0; i < 4; ++i) {
    const int row = row0 + r0 + i;
    if (row >= N) continue;
    #pragma unroll
    for (int j = 0; j < 4; ++j) {
      const int col = col0 + c0 + j;
      C[(size_t)row * KO + col] = acc[i][j] + b[col];
    }
  }
}

// ---- all six per-(node,head) attention dots of one layer in one pass ----
DEVI float dot4f(float4 a, float4 b) { return a.x*b.x + a.y*b.y + a.z*b.z + a.w*b.w; }

__global__ void dot6(const float* __restrict__ hc, const float* __restrict__ hd,
                     const float* __restrict__ ascc, const float* __restrict__ adcc,
                     const float* __restrict__ asdc, const float* __restrict__ addc,
                     const float* __restrict__ ascd, const float* __restrict__ adcd,
                     float* __restrict__ scc, float* __restrict__ dcc,
                     float* __restrict__ ddc, float* __restrict__ scd,
                     float* __restrict__ sdc, float* __restrict__ dcd, int N)
{
  int idx = blockIdx.x * blockDim.x + threadIdx.x;
  if (idx >= N * 4) return;
  int n = idx >> 2, hh = idx & 3;
  const float4* hp = (const float4*)(hc + (size_t)n * HIDn + hh * 32);
  const float4* dp = (const float4*)(hd + (size_t)n * HIDn + hh * 32);
  const float4* a1 = (const float4*)(ascc + hh * 32);
  const float4* a2 = (const float4*)(adcc + hh * 32);
  const float4* a3 = (const float4*)(addc + hh * 32);
  const float4* a4 = (const float4*)(ascd + hh * 32);
  const float4* a5 = (const float4*)(asdc + hh * 32);
  const float4* a6 = (const float4*)(adcd + hh * 32);
  float s1 = 0, s2 = 0, s3 = 0, s4 = 0, t1 = 0, t2 = 0;
  #pragma unroll
  for (int i = 0; i < 8; ++i) {
    float4 hv = hp[i];
    s1 += dot4f(hv, a1[i]);
    s2 += dot4f(hv, a2[i]);
    s3 += dot4f(hv, a3[i]);
    s4 += dot4f(hv, a4[i]);
    float4 dv = dp[i];
    t1 += dot4f(dv, a5[i]);
    t2 += dot4f(dv, a6[i]);
  }
  scc[idx] = s1; dcc[idx] = s2; ddc[idx] = s3;
  scd[idx] = s4; sdc[idx] = t1; dcd[idx] = t2;
}

// ================= CSR build (dst-bucketed edge lists) ===================
__global__ void hist_deg(const int* __restrict__ ei, int* __restrict__ deg)
{
  int e = blockIdx.x * blockDim.x + threadIdx.x;
  if (e < En) atomicAdd(&deg[ei[En + e]], 1);
}

__global__ void scan_offsets(const int* __restrict__ deg, int* __restrict__ offs, int n)
{
  __shared__ int wsum[16];
  __shared__ int carry_sh;
  int tid = threadIdx.x;
  if (tid == 0) { carry_sh = 0; offs[0] = 0; }
  __syncthreads();
  const int nw = blockDim.x >> 6;
  int lane = tid & 63, w = tid >> 6;
  for (int base = 0; base < n; base += blockDim.x) {
    int i = base + tid;
    int v = (i < n) ? deg[i] : 0;
    int x = v;
    #pragma unroll
    for (int off = 1; off < 64; off <<= 1) {
      int y = __shfl_up(x, off);
      if (lane >= off) x += y;
    }
    if (lane == 63) wsum[w] = x;
    __syncthreads();
    if (tid == 0) {
      int s = carry_sh;
      for (int ww = 0; ww < nw; ++ww) { int t = wsum[ww]; wsum[ww] = s; s += t; }
      carry_sh = s;
    }
    __syncthreads();
    if (i < n) offs[i + 1] = wsum[w] + x;
    __syncthreads();
  }
}

__global__ void fill_elist(const int* __restrict__ ei, const int* __restrict__ offs,
                           int* __restrict__ cursor, int2* __restrict__ elist)
{
  int e = blockIdx.x * blockDim.x + threadIdx.x;
  if (e >= En) return;
  int s = ei[e], d = ei[En + e];
  int p = atomicAdd(&cursor[d], 1);
  elist[offs[d] + p] = make_int2(s, e);
}

// ==== FUSED edge attention (CSR): online segmax+denom, then gather =======
__global__ __launch_bounds__(256)
void csr_att(const int* __restrict__ offs, const int2* __restrict__ elist,
             const float* __restrict__ sdot, const float* __restrict__ ddot,
             const float* __restrict__ hsrc, float* __restrict__ out, int Ndst)
{
  int wave = (blockIdx.x * 256 + threadIdx.x) >> 6;
  if (wave >= Ndst) return;
  const int lane = threadIdx.x & 63;
  const int dst = wave;
  const int i0 = offs[dst], i1 = offs[dst + 1];

  // ---- phase A: per-head running max m and denominator den ----
  const int hA = lane & 3;
  const float ddA = ddot[dst * 4 + hA];
  float m = -INFINITY, den = 0.f;
  for (int base = i0; base < i1; base += 16) {
    int i = base + (lane >> 2);
    float l;
    if (i < i1) {
      int srcn = elist[i].x;
      float lv = sdot[srcn * 4 + hA] + ddA;
      l = (lv > 0.f) ? lv : 0.2f * lv;            // leaky_relu(0.2)
    } else l = -INFINITY;
    float mx = l;
    #pragma unroll
    for (int off = 4; off < 64; off <<= 1) mx = fmaxf(mx, __shfl_xor(mx, off));
    float mnew = fmaxf(m, mx);
    float ex = __expf(l - mnew);
    #pragma unroll
    for (int off = 4; off < 64; off <<= 1) ex += __shfl_xor(ex, off);
    den = den * __expf(m - mnew) + ex;
    m = mnew;
  }

  const int hB = lane >> 4;
  float mB   = __shfl(m, hB);
  float dinv = __shfl(den, hB);
  dinv = 1.f / (dinv + 1e-16f);
  const float ddB = ddot[dst * 4 + hB];

  // ---- phase B: gather alpha * h_src (2-way unrolled), fused relu ----
  float a0 = 0.f, a1 = 0.f;
  int i = i0;
  for (; i + 2 <= i1; i += 2) {
    int2 seA = elist[i], seB = elist[i + 1];
    float lA = sdot[seA.x * 4 + hB] + ddB; lA = (lA > 0.f) ? lA : 0.2f * lA;
    float lB = sdot[seB.x * 4 + hB] + ddB; lB = (lB > 0.f) ? lB : 0.2f * lB;
    float alA = __expf(lA - mB) * dinv;
    float alB = __expf(lB - mB) * dinv;
    float2 hvA = *(const float2*)(hsrc + (size_t)seA.x * HIDn + lane * 2);
    float2 hvB = *(const float2*)(hsrc + (size_t)seB.x * HIDn + lane * 2);
    a0 += hvA.x * alA + hvB.x * alB;
    a1 += hvA.y * alA + hvB.y * alB;
  }
  if (i < i1) {
    int2 se = elist[i];
    float lv = sdot[se.x * 4 + hB] + ddB; lv = (lv > 0.f) ? lv : 0.2f * lv;
    float alpha = __expf(lv - mB) * dinv;
    float2 hv = *(const float2*)(hsrc + (size_t)se.x * HIDn + lane * 2);
    a0 += hv.x * alpha;
    a1 += hv.y * alpha;
  }
  float2 o2;
  o2.x = fmaxf(a0, 0.f);
  o2.y = fmaxf(a1, 0.f);
  *(float2*)(out + (size_t)dst * HIDn + lane * 2) = o2;
}

// ---- fallback path (atomic scatter), used only if ws too small ----------
__global__ void edge_logit_max(const int* __restrict__ ei,
                               const float* __restrict__ sdot,
                               const float* __restrict__ ddot,
                               unsigned* __restrict__ m)
{
  int e = blockIdx.x * blockDim.x + threadIdx.x;
  if (e >= En) return;
  int s = ei[e], d = ei[En + e];
  #pragma unroll
  for (int hh = 0; hh < 4; ++hh) {
    float l = sdot[s * 4 + hh] + ddot[d * 4 + hh];
    l = (l > 0.f) ? l : 0.2f * l;
    atomicMax(&m[d * 4 + hh], fmap(l));
  }
}

__global__ void edge_exp_sum(const int* __restrict__ ei,
                             const float* __restrict__ sdot,
                             const float* __restrict__ ddot,
                             const unsigned* __restrict__ m,
                             float* __restrict__ sden,
                             float* __restrict__ ebuf)
{
  int e = blockIdx.x * blockDim.x + threadIdx.x;
  if (e >= En) return;
  int s = ei[e], d = ei[En + e];
  #pragma unroll
  for (int hh = 0; hh < 4; ++hh) {
    float l = sdot[s * 4 + hh] + ddot[d * 4 + hh];
    l = (l > 0.f) ? l : 0.2f * l;
    float ex = expf(fminf(l - fdecode(m[d * 4 + hh]), 0.f));
    ebuf[e * 4 + hh] = ex;
    atomicAdd(&sden[d * 4 + hh], ex);
  }
}

__global__ __launch_bounds__(256)
void edge_scatter(const int* __restrict__ ei, const float* __restrict__ hsrc,
                  const float* __restrict__ ebuf, const float* __restrict__ sden,
                  float* __restrict__ out)
{
  int gid  = blockIdx.x * 256 + threadIdx.x;
  int e    = gid >> 6;
  if (e >= En) return;
  int lane = gid & 63;
  int s = ei[e], d = ei[En + e];
  #pragma unroll
  for (int half = 0; half < 2; ++half) {
    int c  = lane + half * 64;
    int hh = c >> 5;
    float alpha = ebuf[e * 4 + hh] / (sden[d * 4 + hh] + 1e-16f);
    atomicAdd(&out[(size_t)d * HIDn + c], hsrc[(size_t)s * HIDn + c] * alpha);
  }
}

__global__ void relu_k(float* __restrict__ x, int n)
{
  int i = blockIdx.x * blockDim.x + threadIdx.x;
  if (i < n) x[i] = fmaxf(x[i], 0.f);
}

// ---- semantic-attention score, gemm-style 4x4 register blocking ---------
// grid (ntiles, 2 col-halves, 2 inputs); slots[z] += (1/N)*sum q*tanh(o@kW+kb)
__global__ __launch_bounds__(256)
void score_gemm(const float* __restrict__ oA, const float* __restrict__ oB,
                const float* __restrict__ kW, const float* __restrict__ kb,
                const float* __restrict__ q, int N, float* __restrict__ slots)
{
  __shared__ float At[32][68];
  __shared__ float Ws[32][68];
  __shared__ float partw[4];
  const float* o = blockIdx.z ? oB : oA;
  const int row0 = blockIdx.x * 64;
  const int col0 = blockIdx.y * 64;
  const int tid  = threadIdx.x;
  const int r0 = (tid >> 4) << 2;
  const int c0 = (tid & 15) << 2;
  float acc[4][4] = {{0.f, 0.f, 0.f, 0.f}};

  for (int k0 = 0; k0 < 128; k0 += 32) {
    {
      const int r  = tid >> 2;
      const int kq = (tid & 3) << 3;
      const int row = row0 + r;
      float tmp[8];
      if (row < N) {
        const float* ap = o + (size_t)row * HIDn + k0 + kq;
        #pragma unroll
        for (int i = 0; i < 8; ++i) tmp[i] = ap[i];
      } else {
        #pragma unroll
        for (int i = 0; i < 8; ++i) tmp[i] = 0.f;
      }
      #pragma unroll
      for (int i = 0; i < 8; ++i) At[kq + i][r] = tmp[i];
    }
    {
      const int k  = tid >> 3;
      const int cq = (tid & 7) << 3;
      const float* wp = kW + (size_t)(k0 + k) * HIDn + col0 + cq;
      #pragma unroll
      for (int i = 0; i < 8; ++i) Ws[k][cq + i] = wp[i];
    }
    __syncthreads();
    #pragma unroll
    for (int k = 0; k < 32; ++k) {
      float av[4], wvv[4];
      #pragma unroll
      for (int i = 0; i < 4; ++i) av[i] = At[k][r0 + i];
      #pragma unroll
      for (int j = 0; j < 4; ++j) wvv[j] = Ws[k][c0 + j];
      #pragma unroll
      for (int i = 0; i < 4; ++i) {
        #pragma unroll
        for (int j = 0; j < 4; ++j) acc[i][j] += av[i] * wvv[j];
      }
    }
    __syncthreads();
  }

  float sum = 0.f;
  #pragma unroll
  for (int i = 0; i < 4; ++i) {
    int row = row0 + r0 + i;
    if (row >= N) continue;
    #pragma unroll
    for (int j = 0; j < 4; ++j) {
      int col = col0 + c0 + j;
      sum += q[col] * tanhf(acc[i][j] + kb[col]);
    }
  }
  #pragma unroll
  for (int off = 32; off > 0; off >>= 1) sum += __shfl_down(sum, off);
  int wid = tid >> 6, lane = tid & 63;
  if (lane == 0) partw[wid] = sum;
  __syncthreads();
  if (tid == 0)
    atomicAdd(&slots[blockIdx.z],
              (partw[0] + partw[1] + partw[2] + partw[3]) * (1.f / (float)N));
}

__global__ void softmax2_kernel(float* sb)   // sb[0],sb[1] -> weights sb[2],sb[3]
{
  float s0 = sb[0], s1 = sb[1];
  float mx = fmaxf(s0, s1);
  float e0 = expf(s0 - mx), e1 = expf(s1 - mx);
  float inv = 1.f / (e0 + e1);
  sb[2] = e0 * inv;
  sb[3] = e1 * inv;
}

// ---- final projection, gemm-style 4x4 blocking, fused input transform ---
template<int MODE, bool NORM>
__global__ __launch_bounds__(256)
void proj_gemm(const float* __restrict__ fa, const float* __restrict__ fb,
               const float* __restrict__ wv,
               const float* __restrict__ pW, const float* __restrict__ pb,
               float* __restrict__ out, int N)
{
  __shared__ float At[32][68];
  __shared__ float Ws[32][68];
  float w2 = 0.f, w3 = 0.f;
  if (MODE == 2) { w2 = wv[2]; w3 = wv[3]; }
  const int row0 = blockIdx.x * 64;
  const int tid  = threadIdx.x;
  const int r0 = (tid >> 4) << 2;
  const int c0 = (tid & 15) << 2;     // 16 groups x 4 = all 64 cols
  float acc[4][4] = {{0.f, 0.f, 0.f, 0.f}};

  for (int k0 = 0; k0 < 128; k0 += 32) {
    {
      const int r  = tid >> 2;
      const int kq = (tid & 3) << 3;
      const int row = row0 + r;
      float tmp[8];
      if (row < N) {
        #pragma unroll
        for (int i = 0; i < 8; ++i)
          tmp[i] = xform<MODE>(fa, fb, w2, w3, (size_t)row * HIDn + k0 + kq + i);
      } else {
        #pragma unroll
        for (int i = 0; i < 8; ++i) tmp[i] = 0.f;
      }
      #pragma unroll
      for (int i = 0; i < 8; ++i) At[kq + i][r] = tmp[i];
    }
    {
      const int k  = tid >> 3;
      const int cq = (tid & 7) << 3;
      const float* wp = pW + (size_t)(k0 + k) * OUTn + cq;
      #pragma unroll
      for (int i = 0; i < 8; ++i) Ws[k][cq + i] = wp[i];
    }
    __syncthreads();
    #pragma unroll
    for (int k = 0; k < 32; ++k) {
      float av[4], wvv[4];
      #pragma unroll
      for (int i = 0; i < 4; ++i) av[i] = At[k][r0 + i];
      #pragma unroll
      for (int j = 0; j < 4; ++j) wvv[j] = Ws[k][c0 + j];
      #pragma unroll
      for (int i = 0; i < 4; ++i) {
        #pragma unroll
        for (int j = 0; j < 4; ++j) acc[i][j] += av[i] * wvv[j];
      }
    }
    __syncthreads();
  }

  float a[4][4];
  #pragma unroll
  for (int i = 0; i < 4; ++i)
    #pragma unroll
    for (int j = 0; j < 4; ++j) a[i][j] = acc[i][j] + pb[c0 + j];

  if (NORM) {
    // row sums of squares span the 16 consecutive lanes sharing r0
    #pragma unroll
    for (int i = 0; i < 4; ++i) {
      float ss = a[i][0]*a[i][0] + a[i][1]*a[i][1] + a[i][2]*a[i][2] + a[i][3]*a[i][3];
      #pragma unroll
      for (int off = 1; off < 16; off <<= 1) ss += __shfl_xor(ss, off);
      float inv = 1.f / fmaxf(sqrtf(ss), 1e-12f);
      #pragma unroll
      for (int j = 0; j < 4; ++j) a[i][j] *= inv;
    }
  }

  #pragma unroll
  for (int i = 0; i < 4; ++i) {
    int row = row0 + r0 + i;
    if (row >= N) continue;
    #pragma unroll
    for (int j = 0; j < 4; ++j)
      out[(size_t)row * OUTn + c0 + j] = a[i][j];
  }
}

// ---- edge-op dispatcher --------------------------------------------------
static void run_edge(hipStream_t stream, bool useCsr,
                     const int* offs, const int2* elist, const int* ei,
                     const float* sdot, const float* ddot, const float* hsrc,
                     float* outb, int Ndst,
                     unsigned* mbuf, float* sden, float* ebuf)
{
  if (useCsr) {
    csr_att<<<(Ndst + 3) / 4, 256, 0, stream>>>(offs, elist, sdot, ddot, hsrc, outb, Ndst);
  } else {
    hipMemsetAsync(mbuf, 0, (size_t)Ndst * 4 * sizeof(unsigned), stream);
    edge_logit_max<<<(En + 255) / 256, 256, 0, stream>>>(ei, sdot, ddot, mbuf);
    hipMemsetAsync(sden, 0, (size_t)Ndst * 4 * sizeof(float), stream);
    edge_exp_sum<<<(En + 255) / 256, 256, 0, stream>>>(ei, sdot, ddot, mbuf, sden, ebuf);
    hipMemsetAsync(outb, 0, (size_t)Ndst * HIDn * sizeof(float), stream);
    edge_scatter<<<((size_t)En * 64 + 255) / 256, 256, 0, stream>>>(ei, hsrc, ebuf, sden, outb);
    relu_k<<<((size_t)Ndst * HIDn + 255) / 256, 256, 0, stream>>>(outb, Ndst * HIDn);
  }
}

static void build_csr(hipStream_t stream, const int* ei, int* offs, int2* elist, int* tmp)
{
  hipMemsetAsync(tmp, 0, 50000 * sizeof(int), stream);
  hist_deg<<<(En + 255) / 256, 256, 0, stream>>>(ei, tmp);
  scan_offsets<<<1, 1024, 0, stream>>>(tmp, offs, 50000);
  hipMemsetAsync(tmp, 0, 50000 * sizeof(int), stream);
  fill_elist<<<(En + 255) / 256, 256, 0, stream>>>(ei, offs, tmp, elist);
}

extern "C" void kernel_launch(void* const* d_in, const int* in_sizes, int n_in,
                              void* d_out, int out_size, void* d_ws, size_t ws_size,
                              hipStream_t stream)
{
  const float* xc    = (const float*)d_in[0];
  const float* xd    = (const float*)d_in[1];
  const int*   ei_cc = (const int*)d_in[2];
  const int*   ei_dc = (const int*)d_in[3];
  const int*   ei_cd = (const int*)d_in[4];
  const float* W1c = (const float*)d_in[5];  const float* b1c = (const float*)d_in[6];
  const float* W1d = (const float*)d_in[7];  const float* b1d = (const float*)d_in[8];
  const float* a1s_cc = (const float*)d_in[9];  const float* a1d_cc = (const float*)d_in[10];
  const float* a1s_dc = (const float*)d_in[11]; const float* a1d_dc = (const float*)d_in[12];
  const float* a1s_cd = (const float*)d_in[13]; const float* a1d_cd = (const float*)d_in[14];
  const float* k1W = (const float*)d_in[15]; const float* k1b = (const float*)d_in[16];
  const float* q1  = (const float*)d_in[17];
  const float* W2c = (const float*)d_in[18]; const float* b2c = (const float*)d_in[19];
  const float* W2d = (const float*)d_in[20]; const float* b2d = (const float*)d_in[21];
  const float* a2s_cc = (const float*)d_in[22]; const float* a2d_cc = (const float*)d_in[23];
  const float* a2s_dc = (const float*)d_in[24]; const float* a2d_dc = (const float*)d_in[25];
  const float* a2s_cd = (const float*)d_in[26]; const float* a2d_cd = (const float*)d_in[27];
  const float* k2W = (const float*)d_in[28]; const float* k2b = (const float*)d_in[29];
  const float* q2  = (const float*)d_in[30];
  const float* pW  = (const float*)d_in[31]; const float* pb  = (const float*)d_in[32];

  // ---------------- workspace layout (fp32) ----------------
  float* ws = (float*)d_ws;
  const size_t NB = (size_t)NCn * HIDn;           // 6,400,000 floats per node buffer
  float* B0 = ws;
  float* B1 = ws + NB;
  float* B2 = ws + 2 * NB;
  float* B3 = ws + 3 * NB;
  float* B4 = ws + 4 * NB;
  float* sml = ws + 5 * NB;
  // six dot arrays (N*4 each)
  float* scc = sml;
  float* dcc = sml + 200000;
  float* ddc = sml + 400000;
  float* scd = sml + 600000;
  float* sdc = sml + 800000;
  float* dcd = sml + 1000000;
  float* scoreB = sml + 1200000;                 // 16 floats: [s0,s1,w0,w1, s0',s1',w0',w1',...]
  float* R0 = sml + 1200016;                     // shared region: CSR or fallback temps
  // fallback temps inside R0
  unsigned* mbuf = (unsigned*)R0;                // N*4
  float*    sden = R0 + 200000;                  // N*4
  float*    ebuf = R0 + 400000;                  // E*4

  const size_t GSTRIDE = 900016;                 // offs 50004 + elist 800000 + tmp 50000 (+pad)
  const size_t REQ_FLOATS = 5 * NB + 1200016 + 3 * GSTRIDE;   // 35,900,064
  const bool useCsr = ws_size >= REQ_FLOATS * sizeof(float);

  int*  offsG[3] = {nullptr, nullptr, nullptr};
  int2* elG[3]   = {nullptr, nullptr, nullptr};
  const int* eis[3] = {ei_cc, ei_dc, ei_cd};
  if (useCsr) {
    for (int g = 0; g < 3; ++g) {
      int* base = (int*)(R0 + (size_t)g * GSTRIDE);
      offsG[g] = base;
      elG[g]   = (int2*)(base + 50004);
      int* tmp = base + 50004 + 800000;
      build_csr(stream, eis[g], offsG[g], elG[g], tmp);
    }
  }

  hipMemsetAsync(scoreB, 0, 8 * sizeof(float), stream);

  const dim3 gemmGrid((NCn + 63) / 64, HIDn / 64);
  const int NT = (NCn + 63) / 64;
  const int dotGrid = (NCn * 4 + 255) / 256;

  // ---------------- layer 1 ----------------
  gemm_bias<256, 0><<<gemmGrid, 256, 0, stream>>>(xc, nullptr, nullptr, W1c, b1c, B0, NCn, HIDn);
  gemm_bias<256, 0><<<gemmGrid, 256, 0, stream>>>(xd, nullptr, nullptr, W1d, b1d, B1, NDn, HIDn);

  dot6<<<dotGrid, 256, 0, stream>>>(B0, B1, a1s_cc, a1d_cc, a1s_dc, a1d_dc, a1s_cd, a1d_cd,
                                    scc, dcc, ddc, scd, sdc, dcd, NCn);

  run_edge(stream, useCsr, offsG[0], elG[0], ei_cc, scc, dcc, B0, B2, NCn, mbuf, sden, ebuf);
  run_edge(stream, useCsr, offsG[1], elG[1], ei_dc, sdc, ddc, B1, B3, NCn, mbuf, sden, ebuf);
  run_edge(stream, useCsr, offsG[2], elG[2], ei_cd, scd, dcd, B0, B4, NDn, mbuf, sden, ebuf);

  score_gemm<<<dim3(NT, 2, 2), 256, 0, stream>>>(B2, B3, k1W, k1b, q1, NCn, scoreB);
  softmax2_kernel<<<1, 1, 0, stream>>>(scoreB);

  // ---------------- layer 2 (combine/elu fused into A-loads) ----------------
  gemm_bias<128, 2><<<gemmGrid, 256, 0, stream>>>(B2, B3, scoreB, W2c, b2c, B0, NCn, HIDn);
  gemm_bias<128, 1><<<gemmGrid, 256, 0, stream>>>(B4, nullptr, nullptr, W2d, b2d, B1, NDn, HIDn);

  dot6<<<dotGrid, 256, 0, stream>>>(B0, B1, a2s_cc, a2d_cc, a2s_dc, a2d_dc, a2s_cd, a2d_cd,
                                    scc, dcc, ddc, scd, sdc, dcd, NCn);

  run_edge(stream, useCsr, offsG[0], elG[0], ei_cc, scc, dcc, B0, B2, NCn, mbuf, sden, ebuf);
  run_edge(stream, useCsr, offsG[1], elG[1], ei_dc, sdc, ddc, B1, B3, NCn, mbuf, sden, ebuf);
  run_edge(stream, useCsr, offsG[2], elG[2], ei_cd, scd, dcd, B0, B4, NDn, mbuf, sden, ebuf);

  score_gemm<<<dim3(NT, 2, 2), 256, 0, stream>>>(B2, B3, k2W, k2b, q2, NCn, scoreB + 4);
  softmax2_kernel<<<1, 1, 0, stream>>>(scoreB + 4);

  // ---------------- projection (+combine/elu fused) ----------------
  proj_gemm<2, true ><<<NT, 256, 0, stream>>>(B2, B3, scoreB + 4, pW, pb, (float*)d_out, NCn);
  proj_gemm<1, false><<<NT, 256, 0, stream>>>(B4, nullptr, nullptr, pW, pb,
                                              (float*)d_out + (size_t)NCn * OUTn, NDn);
}

// Round 7
// 915.772 us; speedup vs baseline: 3.9236x; 3.9236x over previous
//
#include <hip/hip_runtime.h>
#include <cmath>

#define DEVI static __device__ __forceinline__

constexpr int HIDn = 128, OUTn = 64;
constexpr int NCn = 50000, NDn = 50000, En = 400000;

// monotonic float->uint mapping for atomicMax on floats (handles signs)
DEVI unsigned fmap(float f) {
  int i = __float_as_int(f);
  return (i < 0) ? ~((unsigned)i) : (((unsigned)i) | 0x80000000u);
}
DEVI float fdecode(unsigned u) {
  int i = (u & 0x80000000u) ? (int)(u & 0x7fffffffu) : (int)(~u);
  return __int_as_float(i);
}

// ---- vectorized 8-wide A-row load + fused transform (value-based!) ------
// MODE: 0=plain, 1=elu(x), 2=elu(w2*a+w3*b).  base must be 16B-aligned.
template<int MODE>
DEVI void loadrow8(float* __restrict__ tmp,
                   const float* __restrict__ A, const float* __restrict__ A2,
                   float w2, float w3, size_t base)
{
  const float4* p = (const float4*)(A + base);
  float4 u0 = p[0], u1 = p[1];
  float v[8] = {u0.x, u0.y, u0.z, u0.w, u1.x, u1.y, u1.z, u1.w};
  if (MODE == 2) {
    const float4* q = (const float4*)(A2 + base);
    float4 t0 = q[0], t1 = q[1];
    float vb[8] = {t0.x, t0.y, t0.z, t0.w, t1.x, t1.y, t1.z, t1.w};
    #pragma unroll
    for (int i = 0; i < 8; ++i) v[i] = w2 * v[i] + w3 * vb[i];
  }
  if (MODE >= 1) {
    #pragma unroll
    for (int i = 0; i < 8; ++i) v[i] = (v[i] > 0.f) ? v[i] : (__expf(v[i]) - 1.f);
  }
  #pragma unroll
  for (int i = 0; i < 8; ++i) tmp[i] = v[i];
}

// ---------------- GEMM: C[N,KO] = xform(A)[N,KI] @ W[KI,KO] + b ----------
template<int KI, int MODE>
__global__ __launch_bounds__(256)
void gemm_bias(const float* __restrict__ A, const float* __restrict__ A2,
               const float* __restrict__ wv,
               const float* __restrict__ W, const float* __restrict__ b,
               float* __restrict__ C, int N, int KO)
{
  __shared__ float At[32][68];   // A^T chunk: [k][row]
  __shared__ float Ws[32][68];   // W chunk:   [k][col]
  float w2 = 0.f, w3 = 0.f;
  if (MODE == 2) { w2 = wv[2]; w3 = wv[3]; }
  const int row0 = blockIdx.x * 64;
  const int col0 = blockIdx.y * 64;
  const int tid  = threadIdx.x;
  const int r0 = (tid >> 4) << 2;
  const int c0 = (tid & 15) << 2;
  float acc[4][4] = {{0.f, 0.f, 0.f, 0.f}};

  for (int k0 = 0; k0 < KI; k0 += 32) {
    {
      const int r  = tid >> 2;
      const int kq = (tid & 3) << 3;
      const int row = row0 + r;
      float tmp[8];
      if (row < N) {
        loadrow8<MODE>(tmp, A, A2, w2, w3, (size_t)row * KI + k0 + kq);
      } else {
        #pragma unroll
        for (int i = 0; i < 8; ++i) tmp[i] = 0.f;
      }
      #pragma unroll
      for (int i = 0; i < 8; ++i) At[kq + i][r] = tmp[i];
    }
    {
      const int k  = tid >> 3;
      const int cq = (tid & 7) << 3;
      const float* wp = W + (size_t)(k0 + k) * KO + col0 + cq;
      #pragma unroll
      for (int i = 0; i < 8; ++i) Ws[k][cq + i] = wp[i];
    }
    __syncthreads();
    #pragma unroll
    for (int k = 0; k < 32; ++k) {
      float av[4], wvv[4];
      #pragma unroll
      for (int i = 0; i < 4; ++i) av[i] = At[k][r0 + i];
      #pragma unroll
      for (int j = 0; j < 4; ++j) wvv[j] = Ws[k][c0 + j];
      #pragma unroll
      for (int i = 0; i < 4; ++i) {
        #pragma unroll
        for (int j = 0; j < 4; ++j) acc[i][j] += av[i] * wvv[j];
      }
    }
    __syncthreads();
  }

  #pragma unroll
  for (int i = 0; i < 4; ++i) {
    const int row = row0 + r0 + i;
    if (row >= N) continue;
    #pragma unroll
    for (int j = 0; j < 4; ++j) {
      const int col = col0 + c0 + j;
      C[(size_t)row * KO + col] = acc[i][j] + b[col];
    }
  }
}

// ---- all six per-(node,head) attention dots of one layer in one pass ----
DEVI float dot4f(float4 a, float4 b) { return a.x*b.x + a.y*b.y + a.z*b.z + a.w*b.w; }

__global__ void dot6(const float* __restrict__ hc, const float* __restrict__ hd,
                     const float* __restrict__ ascc, const float* __restrict__ adcc,
                     const float* __restrict__ asdc, const float* __restrict__ addc,
                     const float* __restrict__ ascd, const float* __restrict__ adcd,
                     float* __restrict__ scc, float* __restrict__ dcc,
                     float* __restrict__ ddc, float* __restrict__ scd,
                     float* __restrict__ sdc, float* __restrict__ dcd, int N)
{
  int idx = blockIdx.x * blockDim.x + threadIdx.x;
  if (idx >= N * 4) return;
  int n = idx >> 2, hh = idx & 3;
  const float4* hp = (const float4*)(hc + (size_t)n * HIDn + hh * 32);
  const float4* dp = (const float4*)(hd + (size_t)n * HIDn + hh * 32);
  const float4* a1 = (const float4*)(ascc + hh * 32);
  const float4* a2 = (const float4*)(adcc + hh * 32);
  const float4* a3 = (const float4*)(addc + hh * 32);
  const float4* a4 = (const float4*)(ascd + hh * 32);
  const float4* a5 = (const float4*)(asdc + hh * 32);
  const float4* a6 = (const float4*)(adcd + hh * 32);
  float s1 = 0, s2 = 0, s3 = 0, s4 = 0, t1 = 0, t2 = 0;
  #pragma unroll
  for (int i = 0; i < 8; ++i) {
    float4 hv = hp[i];
    s1 += dot4f(hv, a1[i]);
    s2 += dot4f(hv, a2[i]);
    s3 += dot4f(hv, a3[i]);
    s4 += dot4f(hv, a4[i]);
    float4 dv = dp[i];
    t1 += dot4f(dv, a5[i]);
    t2 += dot4f(dv, a6[i]);
  }
  scc[idx] = s1; dcc[idx] = s2; ddc[idx] = s3;
  scd[idx] = s4; sdc[idx] = t1; dcd[idx] = t2;
}

// ================= CSR build (dst-bucketed edge lists) ===================
__global__ void hist_deg(const int* __restrict__ ei, int* __restrict__ deg)
{
  int e = blockIdx.x * blockDim.x + threadIdx.x;
  if (e < En) atomicAdd(&deg[ei[En + e]], 1);
}

__global__ void scan_offsets(const int* __restrict__ deg, int* __restrict__ offs, int n)
{
  __shared__ int wsum[16];
  __shared__ int carry_sh;
  int tid = threadIdx.x;
  if (tid == 0) { carry_sh = 0; offs[0] = 0; }
  __syncthreads();
  const int nw = blockDim.x >> 6;
  int lane = tid & 63, w = tid >> 6;
  for (int base = 0; base < n; base += blockDim.x) {
    int i = base + tid;
    int v = (i < n) ? deg[i] : 0;
    int x = v;
    #pragma unroll
    for (int off = 1; off < 64; off <<= 1) {
      int y = __shfl_up(x, off);
      if (lane >= off) x += y;
    }
    if (lane == 63) wsum[w] = x;
    __syncthreads();
    if (tid == 0) {
      int s = carry_sh;
      for (int ww = 0; ww < nw; ++ww) { int t = wsum[ww]; wsum[ww] = s; s += t; }
      carry_sh = s;
    }
    __syncthreads();
    if (i < n) offs[i + 1] = wsum[w] + x;
    __syncthreads();
  }
}

__global__ void fill_elist(const int* __restrict__ ei, const int* __restrict__ offs,
                           int* __restrict__ cursor, int2* __restrict__ elist)
{
  int e = blockIdx.x * blockDim.x + threadIdx.x;
  if (e >= En) return;
  int s = ei[e], d = ei[En + e];
  int p = atomicAdd(&cursor[d], 1);
  elist[offs[d] + p] = make_int2(s, e);
}

// ==== FUSED edge attention (CSR): online segmax+denom, then gather =======
__global__ __launch_bounds__(256)
void csr_att(const int* __restrict__ offs, const int2* __restrict__ elist,
             const float* __restrict__ sdot, const float* __restrict__ ddot,
             const float* __restrict__ hsrc, float* __restrict__ out, int Ndst)
{
  int wave = (blockIdx.x * 256 + threadIdx.x) >> 6;
  if (wave >= Ndst) return;
  const int lane = threadIdx.x & 63;
  const int dst = wave;
  const int i0 = offs[dst], i1 = offs[dst + 1];

  // ---- phase A: per-head running max m and denominator den ----
  const int hA = lane & 3;
  const float ddA = ddot[dst * 4 + hA];
  float m = -INFINITY, den = 0.f;
  for (int base = i0; base < i1; base += 16) {
    int i = base + (lane >> 2);
    float l;
    if (i < i1) {
      int srcn = elist[i].x;
      float lv = sdot[srcn * 4 + hA] + ddA;
      l = (lv > 0.f) ? lv : 0.2f * lv;            // leaky_relu(0.2)
    } else l = -INFINITY;
    float mx = l;
    #pragma unroll
    for (int off = 4; off < 64; off <<= 1) mx = fmaxf(mx, __shfl_xor(mx, off));
    float mnew = fmaxf(m, mx);
    float ex = __expf(l - mnew);
    #pragma unroll
    for (int off = 4; off < 64; off <<= 1) ex += __shfl_xor(ex, off);
    den = den * __expf(m - mnew) + ex;
    m = mnew;
  }

  const int hB = lane >> 4;
  float mB   = __shfl(m, hB);
  float dinv = __shfl(den, hB);
  dinv = 1.f / (dinv + 1e-16f);
  const float ddB = ddot[dst * 4 + hB];

  // ---- phase B: gather alpha * h_src (2-way unrolled), fused relu ----
  float a0 = 0.f, a1 = 0.f;
  int i = i0;
  for (; i + 2 <= i1; i += 2) {
    int2 seA = elist[i], seB = elist[i + 1];
    float lA = sdot[seA.x * 4 + hB] + ddB; lA = (lA > 0.f) ? lA : 0.2f * lA;
    float lB = sdot[seB.x * 4 + hB] + ddB; lB = (lB > 0.f) ? lB : 0.2f * lB;
    float alA = __expf(lA - mB) * dinv;
    float alB = __expf(lB - mB) * dinv;
    float2 hvA = *(const float2*)(hsrc + (size_t)seA.x * HIDn + lane * 2);
    float2 hvB = *(const float2*)(hsrc + (size_t)seB.x * HIDn + lane * 2);
    a0 += hvA.x * alA + hvB.x * alB;
    a1 += hvA.y * alA + hvB.y * alB;
  }
  if (i < i1) {
    int2 se = elist[i];
    float lv = sdot[se.x * 4 + hB] + ddB; lv = (lv > 0.f) ? lv : 0.2f * lv;
    float alpha = __expf(lv - mB) * dinv;
    float2 hv = *(const float2*)(hsrc + (size_t)se.x * HIDn + lane * 2);
    a0 += hv.x * alpha;
    a1 += hv.y * alpha;
  }
  float2 o2;
  o2.x = fmaxf(a0, 0.f);
  o2.y = fmaxf(a1, 0.f);
  *(float2*)(out + (size_t)dst * HIDn + lane * 2) = o2;
}

// ---- fallback path (atomic scatter), used only if ws too small ----------
__global__ void edge_logit_max(const int* __restrict__ ei,
                               const float* __restrict__ sdot,
                               const float* __restrict__ ddot,
                               unsigned* __restrict__ m)
{
  int e = blockIdx.x * blockDim.x + threadIdx.x;
  if (e >= En) return;
  int s = ei[e], d = ei[En + e];
  #pragma unroll
  for (int hh = 0; hh < 4; ++hh) {
    float l = sdot[s * 4 + hh] + ddot[d * 4 + hh];
    l = (l > 0.f) ? l : 0.2f * l;
    atomicMax(&m[d * 4 + hh], fmap(l));
  }
}

__global__ void edge_exp_sum(const int* __restrict__ ei,
                             const float* __restrict__ sdot,
                             const float* __restrict__ ddot,
                             const unsigned* __restrict__ m,
                             float* __restrict__ sden,
                             float* __restrict__ ebuf)
{
  int e = blockIdx.x * blockDim.x + threadIdx.x;
  if (e >= En) return;
  int s = ei[e], d = ei[En + e];
  #pragma unroll
  for (int hh = 0; hh < 4; ++hh) {
    float l = sdot[s * 4 + hh] + ddot[d * 4 + hh];
    l = (l > 0.f) ? l : 0.2f * l;
    float ex = expf(fminf(l - fdecode(m[d * 4 + hh]), 0.f));
    ebuf[e * 4 + hh] = ex;
    atomicAdd(&sden[d * 4 + hh], ex);
  }
}

__global__ __launch_bounds__(256)
void edge_scatter(const int* __restrict__ ei, const float* __restrict__ hsrc,
                  const float* __restrict__ ebuf, const float* __restrict__ sden,
                  float* __restrict__ out)
{
  int gid  = blockIdx.x * 256 + threadIdx.x;
  int e    = gid >> 6;
  if (e >= En) return;
  int lane = gid & 63;
  int s = ei[e], d = ei[En + e];
  #pragma unroll
  for (int half = 0; half < 2; ++half) {
    int c  = lane + half * 64;
    int hh = c >> 5;
    float alpha = ebuf[e * 4 + hh] / (sden[d * 4 + hh] + 1e-16f);
    atomicAdd(&out[(size_t)d * HIDn + c], hsrc[(size_t)s * HIDn + c] * alpha);
  }
}

__global__ void relu_k(float* __restrict__ x, int n)
{
  int i = blockIdx.x * blockDim.x + threadIdx.x;
  if (i < n) x[i] = fmaxf(x[i], 0.f);
}

// ---- semantic-attention score, gemm-style 4x4 register blocking ---------
// grid (ntiles, 2 col-halves, 2 inputs); slots[z] += (1/N)*sum q*tanh(o@kW+kb)
__global__ __launch_bounds__(256)
void score_gemm(const float* __restrict__ oA, const float* __restrict__ oB,
                const float* __restrict__ kW, const float* __restrict__ kb,
                const float* __restrict__ q, int N, float* __restrict__ slots)
{
  __shared__ float At[32][68];
  __shared__ float Ws[32][68];
  __shared__ float partw[4];
  const float* o = blockIdx.z ? oB : oA;
  const int row0 = blockIdx.x * 64;
  const int col0 = blockIdx.y * 64;
  const int tid  = threadIdx.x;
  const int r0 = (tid >> 4) << 2;
  const int c0 = (tid & 15) << 2;
  float acc[4][4] = {{0.f, 0.f, 0.f, 0.f}};

  for (int k0 = 0; k0 < 128; k0 += 32) {
    {
      const int r  = tid >> 2;
      const int kq = (tid & 3) << 3;
      const int row = row0 + r;
      float tmp[8];
      if (row < N) {
        loadrow8<0>(tmp, o, nullptr, 0.f, 0.f, (size_t)row * HIDn + k0 + kq);
      } else {
        #pragma unroll
        for (int i = 0; i < 8; ++i) tmp[i] = 0.f;
      }
      #pragma unroll
      for (int i = 0; i < 8; ++i) At[kq + i][r] = tmp[i];
    }
    {
      const int k  = tid >> 3;
      const int cq = (tid & 7) << 3;
      const float* wp = kW + (size_t)(k0 + k) * HIDn + col0 + cq;
      #pragma unroll
      for (int i = 0; i < 8; ++i) Ws[k][cq + i] = wp[i];
    }
    __syncthreads();
    #pragma unroll
    for (int k = 0; k < 32; ++k) {
      float av[4], wvv[4];
      #pragma unroll
      for (int i = 0; i < 4; ++i) av[i] = At[k][r0 + i];
      #pragma unroll
      for (int j = 0; j < 4; ++j) wvv[j] = Ws[k][c0 + j];
      #pragma unroll
      for (int i = 0; i < 4; ++i) {
        #pragma unroll
        for (int j = 0; j < 4; ++j) acc[i][j] += av[i] * wvv[j];
      }
    }
    __syncthreads();
  }

  float sum = 0.f;
  #pragma unroll
  for (int i = 0; i < 4; ++i) {
    int row = row0 + r0 + i;
    if (row >= N) continue;
    #pragma unroll
    for (int j = 0; j < 4; ++j) {
      int col = col0 + c0 + j;
      sum += q[col] * tanhf(acc[i][j] + kb[col]);
    }
  }
  #pragma unroll
  for (int off = 32; off > 0; off >>= 1) sum += __shfl_down(sum, off);
  int wid = tid >> 6, lane = tid & 63;
  if (lane == 0) partw[wid] = sum;
  __syncthreads();
  if (tid == 0)
    atomicAdd(&slots[blockIdx.z],
              (partw[0] + partw[1] + partw[2] + partw[3]) * (1.f / (float)N));
}

__global__ void softmax2_kernel(float* sb)   // sb[0],sb[1] -> weights sb[2],sb[3]
{
  float s0 = sb[0], s1 = sb[1];
  float mx = fmaxf(s0, s1);
  float e0 = expf(s0 - mx), e1 = expf(s1 - mx);
  float inv = 1.f / (e0 + e1);
  sb[2] = e0 * inv;
  sb[3] = e1 * inv;
}

// ---- final projection, gemm-style 4x4 blocking, fused input transform ---
template<int MODE, bool NORM>
__global__ __launch_bounds__(256)
void proj_gemm(const float* __restrict__ fa, const float* __restrict__ fb,
               const float* __restrict__ wv,
               const float* __restrict__ pW, const float* __restrict__ pb,
               float* __restrict__ out, int N)
{
  __shared__ float At[32][68];
  __shared__ float Ws[32][68];
  float w2 = 0.f, w3 = 0.f;
  if (MODE == 2) { w2 = wv[2]; w3 = wv[3]; }
  const int row0 = blockIdx.x * 64;
  const int tid  = threadIdx.x;
  const int r0 = (tid >> 4) << 2;
  const int c0 = (tid & 15) << 2;     // 16 groups x 4 = all 64 cols
  float acc[4][4] = {{0.f, 0.f, 0.f, 0.f}};

  for (int k0 = 0; k0 < 128; k0 += 32) {
    {
      const int r  = tid >> 2;
      const int kq = (tid & 3) << 3;
      const int row = row0 + r;
      float tmp[8];
      if (row < N) {
        loadrow8<MODE>(tmp, fa, fb, w2, w3, (size_t)row * HIDn + k0 + kq);
      } else {
        #pragma unroll
        for (int i = 0; i < 8; ++i) tmp[i] = 0.f;
      }
      #pragma unroll
      for (int i = 0; i < 8; ++i) At[kq + i][r] = tmp[i];
    }
    {
      const int k  = tid >> 3;
      const int cq = (tid & 7) << 3;
      const float* wp = pW + (size_t)(k0 + k) * OUTn + cq;
      #pragma unroll
      for (int i = 0; i < 8; ++i) Ws[k][cq + i] = wp[i];
    }
    __syncthreads();
    #pragma unroll
    for (int k = 0; k < 32; ++k) {
      float av[4], wvv[4];
      #pragma unroll
      for (int i = 0; i < 4; ++i) av[i] = At[k][r0 + i];
      #pragma unroll
      for (int j = 0; j < 4; ++j) wvv[j] = Ws[k][c0 + j];
      #pragma unroll
      for (int i = 0; i < 4; ++i) {
        #pragma unroll
        for (int j = 0; j < 4; ++j) acc[i][j] += av[i] * wvv[j];
      }
    }
    __syncthreads();
  }

  float a[4][4];
  #pragma unroll
  for (int i = 0; i < 4; ++i)
    #pragma unroll
    for (int j = 0; j < 4; ++j) a[i][j] = acc[i][j] + pb[c0 + j];

  if (NORM) {
    // row sums of squares span the 16 consecutive lanes sharing r0
    #pragma unroll
    for (int i = 0; i < 4; ++i) {
      float ss = a[i][0]*a[i][0] + a[i][1]*a[i][1] + a[i][2]*a[i][2] + a[i][3]*a[i][3];
      #pragma unroll
      for (int off = 1; off < 16; off <<= 1) ss += __shfl_xor(ss, off);
      float inv = 1.f / fmaxf(sqrtf(ss), 1e-12f);
      #pragma unroll
      for (int j = 0; j < 4; ++j) a[i][j] *= inv;
    }
  }

  #pragma unroll
  for (int i = 0; i < 4; ++i) {
    int row = row0 + r0 + i;
    if (row >= N) continue;
    #pragma unroll
    for (int j = 0; j < 4; ++j)
      out[(size_t)row * OUTn + c0 + j] = a[i][j];
  }
}

// ---- edge-op dispatcher --------------------------------------------------
static void run_edge(hipStream_t stream, bool useCsr,
                     const int* offs, const int2* elist, const int* ei,
                     const float* sdot, const float* ddot, const float* hsrc,
                     float* outb, int Ndst,
                     unsigned* mbuf, float* sden, float* ebuf)
{
  if (useCsr) {
    csr_att<<<(Ndst + 3) / 4, 256, 0, stream>>>(offs, elist, sdot, ddot, hsrc, outb, Ndst);
  } else {
    hipMemsetAsync(mbuf, 0, (size_t)Ndst * 4 * sizeof(unsigned), stream);
    edge_logit_max<<<(En + 255) / 256, 256, 0, stream>>>(ei, sdot, ddot, mbuf);
    hipMemsetAsync(sden, 0, (size_t)Ndst * 4 * sizeof(float), stream);
    edge_exp_sum<<<(En + 255) / 256, 256, 0, stream>>>(ei, sdot, ddot, mbuf, sden, ebuf);
    hipMemsetAsync(outb, 0, (size_t)Ndst * HIDn * sizeof(float), stream);
    edge_scatter<<<((size_t)En * 64 + 255) / 256, 256, 0, stream>>>(ei, hsrc, ebuf, sden, outb);
    relu_k<<<((size_t)Ndst * HIDn + 255) / 256, 256, 0, stream>>>(outb, Ndst * HIDn);
  }
}

static void build_csr(hipStream_t stream, const int* ei, int* offs, int2* elist, int* tmp)
{
  hipMemsetAsync(tmp, 0, 50000 * sizeof(int), stream);
  hist_deg<<<(En + 255) / 256, 256, 0, stream>>>(ei, tmp);
  scan_offsets<<<1, 1024, 0, stream>>>(tmp, offs, 50000);
  hipMemsetAsync(tmp, 0, 50000 * sizeof(int), stream);
  fill_elist<<<(En + 255) / 256, 256, 0, stream>>>(ei, offs, tmp, elist);
}

extern "C" void kernel_launch(void* const* d_in, const int* in_sizes, int n_in,
                              void* d_out, int out_size, void* d_ws, size_t ws_size,
                              hipStream_t stream)
{
  const float* xc    = (const float*)d_in[0];
  const float* xd    = (const float*)d_in[1];
  const int*   ei_cc = (const int*)d_in[2];
  const int*   ei_dc = (const int*)d_in[3];
  const int*   ei_cd = (const int*)d_in[4];
  const float* W1c = (const float*)d_in[5];  const float* b1c = (const float*)d_in[6];
  const float* W1d = (const float*)d_in[7];  const float* b1d = (const float*)d_in[8];
  const float* a1s_cc = (const float*)d_in[9];  const float* a1d_cc = (const float*)d_in[10];
  const float* a1s_dc = (const float*)d_in[11]; const float* a1d_dc = (const float*)d_in[12];
  const float* a1s_cd = (const float*)d_in[13]; const float* a1d_cd = (const float*)d_in[14];
  const float* k1W = (const float*)d_in[15]; const float* k1b = (const float*)d_in[16];
  const float* q1  = (const float*)d_in[17];
  const float* W2c = (const float*)d_in[18]; const float* b2c = (const float*)d_in[19];
  const float* W2d = (const float*)d_in[20]; const float* b2d = (const float*)d_in[21];
  const float* a2s_cc = (const float*)d_in[22]; const float* a2d_cc = (const float*)d_in[23];
  const float* a2s_dc = (const float*)d_in[24]; const float* a2d_dc = (const float*)d_in[25];
  const float* a2s_cd = (const float*)d_in[26]; const float* a2d_cd = (const float*)d_in[27];
  const float* k2W = (const float*)d_in[28]; const float* k2b = (const float*)d_in[29];
  const float* q2  = (const float*)d_in[30];
  const float* pW  = (const float*)d_in[31]; const float* pb  = (const float*)d_in[32];

  // ---------------- workspace layout (fp32) ----------------
  float* ws = (float*)d_ws;
  const size_t NB = (size_t)NCn * HIDn;           // 6,400,000 floats per node buffer
  float* B0 = ws;
  float* B1 = ws + NB;
  float* B2 = ws + 2 * NB;
  float* B3 = ws + 3 * NB;
  float* B4 = ws + 4 * NB;
  float* sml = ws + 5 * NB;
  // six dot arrays (N*4 each)
  float* scc = sml;
  float* dcc = sml + 200000;
  float* ddc = sml + 400000;
  float* scd = sml + 600000;
  float* sdc = sml + 800000;
  float* dcd = sml + 1000000;
  float* scoreB = sml + 1200000;                 // [s0,s1,w0,w1, s0',s1',w0',w1']
  float* R0 = sml + 1200016;                     // shared region: CSR or fallback temps
  // fallback temps inside R0
  unsigned* mbuf = (unsigned*)R0;                // N*4
  float*    sden = R0 + 200000;                  // N*4
  float*    ebuf = R0 + 400000;                  // E*4

  const size_t GSTRIDE = 900016;                 // offs 50004 + elist 800000 + tmp 50000 (+pad)
  const size_t REQ_FLOATS = 5 * NB + 1200016 + 3 * GSTRIDE;   // 35,900,064
  const bool useCsr = ws_size >= REQ_FLOATS * sizeof(float);

  int*  offsG[3] = {nullptr, nullptr, nullptr};
  int2* elG[3]   = {nullptr, nullptr, nullptr};
  const int* eis[3] = {ei_cc, ei_dc, ei_cd};
  if (useCsr) {
    for (int g = 0; g < 3; ++g) {
      int* base = (int*)(R0 + (size_t)g * GSTRIDE);
      offsG[g] = base;
      elG[g]   = (int2*)(base + 50004);
      int* tmp = base + 50004 + 800000;
      build_csr(stream, eis[g], offsG[g], elG[g], tmp);
    }
  }

  hipMemsetAsync(scoreB, 0, 8 * sizeof(float), stream);

  const dim3 gemmGrid((NCn + 63) / 64, HIDn / 64);
  const int NT = (NCn + 63) / 64;
  const int dotGrid = (NCn * 4 + 255) / 256;

  // ---------------- layer 1 ----------------
  gemm_bias<256, 0><<<gemmGrid, 256, 0, stream>>>(xc, nullptr, nullptr, W1c, b1c, B0, NCn, HIDn);
  gemm_bias<256, 0><<<gemmGrid, 256, 0, stream>>>(xd, nullptr, nullptr, W1d, b1d, B1, NDn, HIDn);

  dot6<<<dotGrid, 256, 0, stream>>>(B0, B1, a1s_cc, a1d_cc, a1s_dc, a1d_dc, a1s_cd, a1d_cd,
                                    scc, dcc, ddc, scd, sdc, dcd, NCn);

  run_edge(stream, useCsr, offsG[0], elG[0], ei_cc, scc, dcc, B0, B2, NCn, mbuf, sden, ebuf);
  run_edge(stream, useCsr, offsG[1], elG[1], ei_dc, sdc, ddc, B1, B3, NCn, mbuf, sden, ebuf);
  run_edge(stream, useCsr, offsG[2], elG[2], ei_cd, scd, dcd, B0, B4, NDn, mbuf, sden, ebuf);

  score_gemm<<<dim3(NT, 2, 2), 256, 0, stream>>>(B2, B3, k1W, k1b, q1, NCn, scoreB);
  softmax2_kernel<<<1, 1, 0, stream>>>(scoreB);

  // ---------------- layer 2 (combine/elu fused into A-loads) ----------------
  gemm_bias<128, 2><<<gemmGrid, 256, 0, stream>>>(B2, B3, scoreB, W2c, b2c, B0, NCn, HIDn);
  gemm_bias<128, 1><<<gemmGrid, 256, 0, stream>>>(B4, nullptr, nullptr, W2d, b2d, B1, NDn, HIDn);

  dot6<<<dotGrid, 256, 0, stream>>>(B0, B1, a2s_cc, a2d_cc, a2s_dc, a2d_dc, a2s_cd, a2d_cd,
                                    scc, dcc, ddc, scd, sdc, dcd, NCn);

  run_edge(stream, useCsr, offsG[0], elG[0], ei_cc, scc, dcc, B0, B2, NCn, mbuf, sden, ebuf);
  run_edge(stream, useCsr, offsG[1], elG[1], ei_dc, sdc, ddc, B1, B3, NCn, mbuf, sden, ebuf);
  run_edge(stream, useCsr, offsG[2], elG[2], ei_cd, scd, dcd, B0, B4, NDn, mbuf, sden, ebuf);

  score_gemm<<<dim3(NT, 2, 2), 256, 0, stream>>>(B2, B3, k2W, k2b, q2, NCn, scoreB + 4);
  softmax2_kernel<<<1, 1, 0, stream>>>(scoreB + 4);

  // ---------------- projection (+combine/elu fused) ----------------
  proj_gemm<2, true ><<<NT, 256, 0, stream>>>(B2, B3, scoreB + 4, pW, pb, (float*)d_out, NCn);
  proj_gemm<1, false><<<NT, 256, 0, stream>>>(B4, nullptr, nullptr, pW, pb,
                                              (float*)d_out + (size_t)NCn * OUTn, NDn);
}

// Round 8
// 755.679 us; speedup vs baseline: 4.7548x; 1.2119x over previous
//
#include <hip/hip_runtime.h>
#include <cmath>

#define DEVI static __device__ __forceinline__

constexpr int HIDn = 128, OUTn = 64;
constexpr int NCn = 50000, NDn = 50000, En = 400000;

// monotonic float->uint mapping for atomicMax on floats (handles signs)
DEVI unsigned fmap(float f) {
  int i = __float_as_int(f);
  return (i < 0) ? ~((unsigned)i) : (((unsigned)i) | 0x80000000u);
}
DEVI float fdecode(unsigned u) {
  int i = (u & 0x80000000u) ? (int)(u & 0x7fffffffu) : (int)(~u);
  return __int_as_float(i);
}

DEVI float tanh_fast(float x) {           // 1 - 2/(e^{2x}+1); saturates correctly
  float e = __expf(2.f * x);
  return 1.f - __fdividef(2.f, e + 1.f);
}

// ---- vectorized 8-wide A-row load + fused transform (value-based) -------
// MODE: 0=plain, 1=elu(x), 2=elu(w2*a+w3*b).  base must be 16B-aligned.
template<int MODE>
DEVI void loadrow8(float* __restrict__ tmp,
                   const float* __restrict__ A, const float* __restrict__ A2,
                   float w2, float w3, size_t base)
{
  const float4* p = (const float4*)(A + base);
  float4 u0 = p[0], u1 = p[1];
  float v[8] = {u0.x, u0.y, u0.z, u0.w, u1.x, u1.y, u1.z, u1.w};
  if (MODE == 2) {
    const float4* q = (const float4*)(A2 + base);
    float4 t0 = q[0], t1 = q[1];
    float vb[8] = {t0.x, t0.y, t0.z, t0.w, t1.x, t1.y, t1.z, t1.w};
    #pragma unroll
    for (int i = 0; i < 8; ++i) v[i] = w2 * v[i] + w3 * vb[i];
  }
  if (MODE >= 1) {
    #pragma unroll
    for (int i = 0; i < 8; ++i) v[i] = (v[i] > 0.f) ? v[i] : (__expf(v[i]) - 1.f);
  }
  #pragma unroll
  for (int i = 0; i < 8; ++i) tmp[i] = v[i];
}

// ---------------- GEMM: C[N,KO] = xform(A)[N,KI] @ W[KI,KO] + b ----------
template<int KI, int MODE>
__global__ __launch_bounds__(256)
void gemm_bias(const float* __restrict__ A, const float* __restrict__ A2,
               const float* __restrict__ wv,
               const float* __restrict__ W, const float* __restrict__ b,
               float* __restrict__ C, int N, int KO)
{
  __shared__ float At[32][68];   // A^T chunk: [k][row]
  __shared__ float Ws[32][68];   // W chunk:   [k][col]
  float w2 = 0.f, w3 = 0.f;
  if (MODE == 2) { w2 = wv[2]; w3 = wv[3]; }
  const int row0 = blockIdx.x * 64;
  const int col0 = blockIdx.y * 64;
  const int tid  = threadIdx.x;
  const int r0 = (tid >> 4) << 2;
  const int c0 = (tid & 15) << 2;
  float acc[4][4] = {{0.f, 0.f, 0.f, 0.f}};

  for (int k0 = 0; k0 < KI; k0 += 32) {
    {
      const int r  = tid >> 2;
      const int kq = (tid & 3) << 3;
      const int row = row0 + r;
      float tmp[8];
      if (row < N) {
        loadrow8<MODE>(tmp, A, A2, w2, w3, (size_t)row * KI + k0 + kq);
      } else {
        #pragma unroll
        for (int i = 0; i < 8; ++i) tmp[i] = 0.f;
      }
      #pragma unroll
      for (int i = 0; i < 8; ++i) At[kq + i][r] = tmp[i];
    }
    {
      const int k  = tid >> 3;
      const int cq = (tid & 7) << 3;
      const float* wp = W + (size_t)(k0 + k) * KO + col0 + cq;
      float4 wa = *(const float4*)(wp);
      float4 wb = *(const float4*)(wp + 4);
      *(float4*)&Ws[k][cq]     = wa;
      *(float4*)&Ws[k][cq + 4] = wb;
    }
    __syncthreads();
    #pragma unroll
    for (int k = 0; k < 32; ++k) {
      float4 av4 = *(const float4*)&At[k][r0];
      float4 wv4 = *(const float4*)&Ws[k][c0];
      float av[4] = {av4.x, av4.y, av4.z, av4.w};
      float wvv[4] = {wv4.x, wv4.y, wv4.z, wv4.w};
      #pragma unroll
      for (int i = 0; i < 4; ++i) {
        #pragma unroll
        for (int j = 0; j < 4; ++j) acc[i][j] += av[i] * wvv[j];
      }
    }
    __syncthreads();
  }

  #pragma unroll
  for (int i = 0; i < 4; ++i) {
    const int row = row0 + r0 + i;
    if (row >= N) continue;
    #pragma unroll
    for (int j = 0; j < 4; ++j) {
      const int col = col0 + c0 + j;
      C[(size_t)row * KO + col] = acc[i][j] + b[col];
    }
  }
}

// ---- all six per-(node,head) attention dots of one layer in one pass ----
DEVI float dot4f(float4 a, float4 b) { return a.x*b.x + a.y*b.y + a.z*b.z + a.w*b.w; }

__global__ void dot6(const float* __restrict__ hc, const float* __restrict__ hd,
                     const float* __restrict__ ascc, const float* __restrict__ adcc,
                     const float* __restrict__ asdc, const float* __restrict__ addc,
                     const float* __restrict__ ascd, const float* __restrict__ adcd,
                     float* __restrict__ scc, float* __restrict__ dcc,
                     float* __restrict__ ddc, float* __restrict__ scd,
                     float* __restrict__ sdc, float* __restrict__ dcd, int N)
{
  int idx = blockIdx.x * blockDim.x + threadIdx.x;
  if (idx >= N * 4) return;
  int n = idx >> 2, hh = idx & 3;
  const float4* hp = (const float4*)(hc + (size_t)n * HIDn + hh * 32);
  const float4* dp = (const float4*)(hd + (size_t)n * HIDn + hh * 32);
  const float4* a1 = (const float4*)(ascc + hh * 32);
  const float4* a2 = (const float4*)(adcc + hh * 32);
  const float4* a3 = (const float4*)(addc + hh * 32);
  const float4* a4 = (const float4*)(ascd + hh * 32);
  const float4* a5 = (const float4*)(asdc + hh * 32);
  const float4* a6 = (const float4*)(adcd + hh * 32);
  float s1 = 0, s2 = 0, s3 = 0, s4 = 0, t1 = 0, t2 = 0;
  #pragma unroll
  for (int i = 0; i < 8; ++i) {
    float4 hv = hp[i];
    s1 += dot4f(hv, a1[i]);
    s2 += dot4f(hv, a2[i]);
    s3 += dot4f(hv, a3[i]);
    s4 += dot4f(hv, a4[i]);
    float4 dv = dp[i];
    t1 += dot4f(dv, a5[i]);
    t2 += dot4f(dv, a6[i]);
  }
  scc[idx] = s1; dcc[idx] = s2; ddc[idx] = s3;
  scd[idx] = s4; sdc[idx] = t1; dcd[idx] = t2;
}

// ================= CSR build, all 3 graphs batched =======================
__global__ void hist3(const int* __restrict__ ei0, const int* __restrict__ ei1,
                      const int* __restrict__ ei2, int* __restrict__ tmpBase)
{
  int gid = blockIdx.x * blockDim.x + threadIdx.x;
  if (gid >= 3 * En) return;
  int g = gid / En, e = gid - g * En;
  const int* ei = (g == 0) ? ei0 : (g == 1) ? ei1 : ei2;
  atomicAdd(&tmpBase[g * 50000 + ei[En + e]], 1);
}

// one block per graph (grid=3, block=1024)
__global__ void scan3(const int* __restrict__ tmpBase, int* __restrict__ offsBase)
{
  const int n = 50000;
  const int* deg = tmpBase + blockIdx.x * 50000;
  int* offs = offsBase + blockIdx.x * 50004;
  __shared__ int wsum[16];
  __shared__ int carry_sh;
  int tid = threadIdx.x;
  if (tid == 0) { carry_sh = 0; offs[0] = 0; }
  __syncthreads();
  const int nw = blockDim.x >> 6;
  int lane = tid & 63, w = tid >> 6;
  for (int base = 0; base < n; base += blockDim.x) {
    int i = base + tid;
    int v = (i < n) ? deg[i] : 0;
    int x = v;
    #pragma unroll
    for (int off = 1; off < 64; off <<= 1) {
      int y = __shfl_up(x, off);
      if (lane >= off) x += y;
    }
    if (lane == 63) wsum[w] = x;
    __syncthreads();
    if (tid == 0) {
      int s = carry_sh;
      for (int ww = 0; ww < nw; ++ww) { int t = wsum[ww]; wsum[ww] = s; s += t; }
      carry_sh = s;
    }
    __syncthreads();
    if (i < n) offs[i + 1] = wsum[w] + x;
    __syncthreads();
  }
}

__global__ void fill3(const int* __restrict__ ei0, const int* __restrict__ ei1,
                      const int* __restrict__ ei2, const int* __restrict__ offsBase,
                      int* __restrict__ cursorBase, int2* __restrict__ elistBase)
{
  int gid = blockIdx.x * blockDim.x + threadIdx.x;
  if (gid >= 3 * En) return;
  int g = gid / En, e = gid - g * En;
  const int* ei = (g == 0) ? ei0 : (g == 1) ? ei1 : ei2;
  const int* offs = offsBase + g * 50004;
  int* cursor = cursorBase + g * 50000;
  int2* elist = elistBase + (size_t)g * En;
  int s = ei[e], d = ei[En + e];
  int p = atomicAdd(&cursor[d], 1);
  elist[offs[d] + p] = make_int2(s, e);
}

// ==== FUSED edge attention (CSR): online segmax+denom, then gather =======
struct EdgeOp {
  const int* offs; const int2* elist;
  const float* sdot; const float* ddot;
  const float* hsrc; float* out;
};

DEVI void csr_att_body(const EdgeOp& op, int dst, int lane)
{
  const int i0 = op.offs[dst], i1 = op.offs[dst + 1];

  // ---- phase A: per-head running max m and denominator den ----
  const int hA = lane & 3;
  const float ddA = op.ddot[dst * 4 + hA];
  float m = -INFINITY, den = 0.f;
  for (int base = i0; base < i1; base += 16) {
    int i = base + (lane >> 2);
    float l;
    if (i < i1) {
      int srcn = op.elist[i].x;
      float lv = op.sdot[srcn * 4 + hA] + ddA;
      l = (lv > 0.f) ? lv : 0.2f * lv;            // leaky_relu(0.2)
    } else l = -INFINITY;
    float mx = l;
    #pragma unroll
    for (int off = 4; off < 64; off <<= 1) mx = fmaxf(mx, __shfl_xor(mx, off));
    float mnew = fmaxf(m, mx);
    float ex = __expf(l - mnew);
    #pragma unroll
    for (int off = 4; off < 64; off <<= 1) ex += __shfl_xor(ex, off);
    den = den * __expf(m - mnew) + ex;
    m = mnew;
  }

  const int hB = lane >> 4;
  float mB   = __shfl(m, hB);
  float dinv = __shfl(den, hB);
  dinv = 1.f / (dinv + 1e-16f);
  const float ddB = op.ddot[dst * 4 + hB];
  const float* hsrc = op.hsrc;

  // ---- phase B: 4-way unrolled gather (loads hoisted ahead of alpha) ----
  float a0 = 0.f, a1 = 0.f;
  int i = i0;
  for (; i + 4 <= i1; i += 4) {
    int2 s0 = op.elist[i],     s1 = op.elist[i + 1];
    int2 s2 = op.elist[i + 2], s3 = op.elist[i + 3];
    float2 h0 = *(const float2*)(hsrc + (size_t)s0.x * HIDn + lane * 2);
    float2 h1 = *(const float2*)(hsrc + (size_t)s1.x * HIDn + lane * 2);
    float2 h2 = *(const float2*)(hsrc + (size_t)s2.x * HIDn + lane * 2);
    float2 h3 = *(const float2*)(hsrc + (size_t)s3.x * HIDn + lane * 2);
    float l0 = op.sdot[s0.x * 4 + hB] + ddB; l0 = (l0 > 0.f) ? l0 : 0.2f * l0;
    float l1 = op.sdot[s1.x * 4 + hB] + ddB; l1 = (l1 > 0.f) ? l1 : 0.2f * l1;
    float l2 = op.sdot[s2.x * 4 + hB] + ddB; l2 = (l2 > 0.f) ? l2 : 0.2f * l2;
    float l3 = op.sdot[s3.x * 4 + hB] + ddB; l3 = (l3 > 0.f) ? l3 : 0.2f * l3;
    float e0 = __expf(l0 - mB) * dinv, e1 = __expf(l1 - mB) * dinv;
    float e2 = __expf(l2 - mB) * dinv, e3 = __expf(l3 - mB) * dinv;
    a0 += h0.x * e0 + h1.x * e1 + h2.x * e2 + h3.x * e3;
    a1 += h0.y * e0 + h1.y * e1 + h2.y * e2 + h3.y * e3;
  }
  for (; i < i1; ++i) {
    int2 se = op.elist[i];
    float2 hv = *(const float2*)(hsrc + (size_t)se.x * HIDn + lane * 2);
    float lv = op.sdot[se.x * 4 + hB] + ddB; lv = (lv > 0.f) ? lv : 0.2f * lv;
    float alpha = __expf(lv - mB) * dinv;
    a0 += hv.x * alpha;
    a1 += hv.y * alpha;
  }
  float2 o2;
  o2.x = fmaxf(a0, 0.f);
  o2.y = fmaxf(a1, 0.f);
  *(float2*)(op.out + (size_t)dst * HIDn + lane * 2) = o2;
}

__global__ __launch_bounds__(256)
void csr_att3(EdgeOp op0, EdgeOp op1, EdgeOp op2, int Ndst)
{
  int wave = (blockIdx.x * 256 + threadIdx.x) >> 6;
  if (wave >= Ndst) return;
  const int lane = threadIdx.x & 63;
  if (blockIdx.y == 0)      csr_att_body(op0, wave, lane);
  else if (blockIdx.y == 1) csr_att_body(op1, wave, lane);
  else                      csr_att_body(op2, wave, lane);
}

// ---- fallback path (atomic scatter), used only if ws too small ----------
__global__ void edge_logit_max(const int* __restrict__ ei,
                               const float* __restrict__ sdot,
                               const float* __restrict__ ddot,
                               unsigned* __restrict__ m)
{
  int e = blockIdx.x * blockDim.x + threadIdx.x;
  if (e >= En) return;
  int s = ei[e], d = ei[En + e];
  #pragma unroll
  for (int hh = 0; hh < 4; ++hh) {
    float l = sdot[s * 4 + hh] + ddot[d * 4 + hh];
    l = (l > 0.f) ? l : 0.2f * l;
    atomicMax(&m[d * 4 + hh], fmap(l));
  }
}

__global__ void edge_exp_sum(const int* __restrict__ ei,
                             const float* __restrict__ sdot,
                             const float* __restrict__ ddot,
                             const unsigned* __restrict__ m,
                             float* __restrict__ sden,
                             float* __restrict__ ebuf)
{
  int e = blockIdx.x * blockDim.x + threadIdx.x;
  if (e >= En) return;
  int s = ei[e], d = ei[En + e];
  #pragma unroll
  for (int hh = 0; hh < 4; ++hh) {
    float l = sdot[s * 4 + hh] + ddot[d * 4 + hh];
    l = (l > 0.f) ? l : 0.2f * l;
    float ex = expf(fminf(l - fdecode(m[d * 4 + hh]), 0.f));
    ebuf[e * 4 + hh] = ex;
    atomicAdd(&sden[d * 4 + hh], ex);
  }
}

__global__ __launch_bounds__(256)
void edge_scatter(const int* __restrict__ ei, const float* __restrict__ hsrc,
                  const float* __restrict__ ebuf, const float* __restrict__ sden,
                  float* __restrict__ out)
{
  int gid  = blockIdx.x * 256 + threadIdx.x;
  int e    = gid >> 6;
  if (e >= En) return;
  int lane = gid & 63;
  int s = ei[e], d = ei[En + e];
  #pragma unroll
  for (int half = 0; half < 2; ++half) {
    int c  = lane + half * 64;
    int hh = c >> 5;
    float alpha = ebuf[e * 4 + hh] / (sden[d * 4 + hh] + 1e-16f);
    atomicAdd(&out[(size_t)d * HIDn + c], hsrc[(size_t)s * HIDn + c] * alpha);
  }
}

__global__ void relu_k(float* __restrict__ x, int n)
{
  int i = blockIdx.x * blockDim.x + threadIdx.x;
  if (i < n) x[i] = fmaxf(x[i], 0.f);
}

// ---- semantic-attention score, gemm-style 4x4 register blocking ---------
__global__ __launch_bounds__(256)
void score_gemm(const float* __restrict__ oA, const float* __restrict__ oB,
                const float* __restrict__ kW, const float* __restrict__ kb,
                const float* __restrict__ q, int N, float* __restrict__ slots)
{
  __shared__ float At[32][68];
  __shared__ float Ws[32][68];
  __shared__ float partw[4];
  const float* o = blockIdx.z ? oB : oA;
  const int row0 = blockIdx.x * 64;
  const int col0 = blockIdx.y * 64;
  const int tid  = threadIdx.x;
  const int r0 = (tid >> 4) << 2;
  const int c0 = (tid & 15) << 2;
  float acc[4][4] = {{0.f, 0.f, 0.f, 0.f}};

  for (int k0 = 0; k0 < 128; k0 += 32) {
    {
      const int r  = tid >> 2;
      const int kq = (tid & 3) << 3;
      const int row = row0 + r;
      float tmp[8];
      if (row < N) {
        loadrow8<0>(tmp, o, nullptr, 0.f, 0.f, (size_t)row * HIDn + k0 + kq);
      } else {
        #pragma unroll
        for (int i = 0; i < 8; ++i) tmp[i] = 0.f;
      }
      #pragma unroll
      for (int i = 0; i < 8; ++i) At[kq + i][r] = tmp[i];
    }
    {
      const int k  = tid >> 3;
      const int cq = (tid & 7) << 3;
      const float* wp = kW + (size_t)(k0 + k) * HIDn + col0 + cq;
      float4 wa = *(const float4*)(wp);
      float4 wb = *(const float4*)(wp + 4);
      *(float4*)&Ws[k][cq]     = wa;
      *(float4*)&Ws[k][cq + 4] = wb;
    }
    __syncthreads();
    #pragma unroll
    for (int k = 0; k < 32; ++k) {
      float4 av4 = *(const float4*)&At[k][r0];
      float4 wv4 = *(const float4*)&Ws[k][c0];
      float av[4] = {av4.x, av4.y, av4.z, av4.w};
      float wvv[4] = {wv4.x, wv4.y, wv4.z, wv4.w};
      #pragma unroll
      for (int i = 0; i < 4; ++i) {
        #pragma unroll
        for (int j = 0; j < 4; ++j) acc[i][j] += av[i] * wvv[j];
      }
    }
    __syncthreads();
  }

  float sum = 0.f;
  #pragma unroll
  for (int i = 0; i < 4; ++i) {
    int row = row0 + r0 + i;
    if (row >= N) continue;
    #pragma unroll
    for (int j = 0; j < 4; ++j) {
      int col = col0 + c0 + j;
      sum += q[col] * tanh_fast(acc[i][j] + kb[col]);
    }
  }
  #pragma unroll
  for (int off = 32; off > 0; off >>= 1) sum += __shfl_down(sum, off);
  int wid = tid >> 6, lane = tid & 63;
  if (lane == 0) partw[wid] = sum;
  __syncthreads();
  if (tid == 0)
    atomicAdd(&slots[blockIdx.z],
              (partw[0] + partw[1] + partw[2] + partw[3]) * (1.f / (float)N));
}

__global__ void softmax2_kernel(float* sb)   // sb[0],sb[1] -> weights sb[2],sb[3]
{
  float s0 = sb[0], s1 = sb[1];
  float mx = fmaxf(s0, s1);
  float e0 = expf(s0 - mx), e1 = expf(s1 - mx);
  float inv = 1.f / (e0 + e1);
  sb[2] = e0 * inv;
  sb[3] = e1 * inv;
}

// ---- final projection, gemm-style 4x4 blocking, fused input transform ---
template<int MODE, bool NORM>
__global__ __launch_bounds__(256)
void proj_gemm(const float* __restrict__ fa, const float* __restrict__ fb,
               const float* __restrict__ wv,
               const float* __restrict__ pW, const float* __restrict__ pb,
               float* __restrict__ out, int N)
{
  __shared__ float At[32][68];
  __shared__ float Ws[32][68];
  float w2 = 0.f, w3 = 0.f;
  if (MODE == 2) { w2 = wv[2]; w3 = wv[3]; }
  const int row0 = blockIdx.x * 64;
  const int tid  = threadIdx.x;
  const int r0 = (tid >> 4) << 2;
  const int c0 = (tid & 15) << 2;     // 16 groups x 4 = all 64 cols
  float acc[4][4] = {{0.f, 0.f, 0.f, 0.f}};

  for (int k0 = 0; k0 < 128; k0 += 32) {
    {
      const int r  = tid >> 2;
      const int kq = (tid & 3) << 3;
      const int row = row0 + r;
      float tmp[8];
      if (row < N) {
        loadrow8<MODE>(tmp, fa, fb, w2, w3, (size_t)row * HIDn + k0 + kq);
      } else {
        #pragma unroll
        for (int i = 0; i < 8; ++i) tmp[i] = 0.f;
      }
      #pragma unroll
      for (int i = 0; i < 8; ++i) At[kq + i][r] = tmp[i];
    }
    {
      const int k  = tid >> 3;
      const int cq = (tid & 7) << 3;
      const float* wp = pW + (size_t)(k0 + k) * OUTn + cq;
      float4 wa = *(const float4*)(wp);
      float4 wb = *(const float4*)(wp + 4);
      *(float4*)&Ws[k][cq]     = wa;
      *(float4*)&Ws[k][cq + 4] = wb;
    }
    __syncthreads();
    #pragma unroll
    for (int k = 0; k < 32; ++k) {
      float4 av4 = *(const float4*)&At[k][r0];
      float4 wv4 = *(const float4*)&Ws[k][c0];
      float av[4] = {av4.x, av4.y, av4.z, av4.w};
      float wvv[4] = {wv4.x, wv4.y, wv4.z, wv4.w};
      #pragma unroll
      for (int i = 0; i < 4; ++i) {
        #pragma unroll
        for (int j = 0; j < 4; ++j) acc[i][j] += av[i] * wvv[j];
      }
    }
    __syncthreads();
  }

  float a[4][4];
  #pragma unroll
  for (int i = 0; i < 4; ++i)
    #pragma unroll
    for (int j = 0; j < 4; ++j) a[i][j] = acc[i][j] + pb[c0 + j];

  if (NORM) {
    #pragma unroll
    for (int i = 0; i < 4; ++i) {
      float ss = a[i][0]*a[i][0] + a[i][1]*a[i][1] + a[i][2]*a[i][2] + a[i][3]*a[i][3];
      #pragma unroll
      for (int off = 1; off < 16; off <<= 1) ss += __shfl_xor(ss, off);
      float inv = 1.f / fmaxf(sqrtf(ss), 1e-12f);
      #pragma unroll
      for (int j = 0; j < 4; ++j) a[i][j] *= inv;
    }
  }

  #pragma unroll
  for (int i = 0; i < 4; ++i) {
    int row = row0 + r0 + i;
    if (row >= N) continue;
    #pragma unroll
    for (int j = 0; j < 4; ++j)
      out[(size_t)row * OUTn + c0 + j] = a[i][j];
  }
}

// ---- fallback edge-op dispatcher ----------------------------------------
static void run_edge_fb(hipStream_t stream, const int* ei,
                        const float* sdot, const float* ddot, const float* hsrc,
                        float* outb, int Ndst,
                        unsigned* mbuf, float* sden, float* ebuf)
{
  hipMemsetAsync(mbuf, 0, (size_t)Ndst * 4 * sizeof(unsigned), stream);
  edge_logit_max<<<(En + 255) / 256, 256, 0, stream>>>(ei, sdot, ddot, mbuf);
  hipMemsetAsync(sden, 0, (size_t)Ndst * 4 * sizeof(float), stream);
  edge_exp_sum<<<(En + 255) / 256, 256, 0, stream>>>(ei, sdot, ddot, mbuf, sden, ebuf);
  hipMemsetAsync(outb, 0, (size_t)Ndst * HIDn * sizeof(float), stream);
  edge_scatter<<<((size_t)En * 64 + 255) / 256, 256, 0, stream>>>(ei, hsrc, ebuf, sden, outb);
  relu_k<<<((size_t)Ndst * HIDn + 255) / 256, 256, 0, stream>>>(outb, Ndst * HIDn);
}

extern "C" void kernel_launch(void* const* d_in, const int* in_sizes, int n_in,
                              void* d_out, int out_size, void* d_ws, size_t ws_size,
                              hipStream_t stream)
{
  const float* xc    = (const float*)d_in[0];
  const float* xd    = (const float*)d_in[1];
  const int*   ei_cc = (const int*)d_in[2];
  const int*   ei_dc = (const int*)d_in[3];
  const int*   ei_cd = (const int*)d_in[4];
  const float* W1c = (const float*)d_in[5];  const float* b1c = (const float*)d_in[6];
  const float* W1d = (const float*)d_in[7];  const float* b1d = (const float*)d_in[8];
  const float* a1s_cc = (const float*)d_in[9];  const float* a1d_cc = (const float*)d_in[10];
  const float* a1s_dc = (const float*)d_in[11]; const float* a1d_dc = (const float*)d_in[12];
  const float* a1s_cd = (const float*)d_in[13]; const float* a1d_cd = (const float*)d_in[14];
  const float* k1W = (const float*)d_in[15]; const float* k1b = (const float*)d_in[16];
  const float* q1  = (const float*)d_in[17];
  const float* W2c = (const float*)d_in[18]; const float* b2c = (const float*)d_in[19];
  const float* W2d = (const float*)d_in[20]; const float* b2d = (const float*)d_in[21];
  const float* a2s_cc = (const float*)d_in[22]; const float* a2d_cc = (const float*)d_in[23];
  const float* a2s_dc = (const float*)d_in[24]; const float* a2d_dc = (const float*)d_in[25];
  const float* a2s_cd = (const float*)d_in[26]; const float* a2d_cd = (const float*)d_in[27];
  const float* k2W = (const float*)d_in[28]; const float* k2b = (const float*)d_in[29];
  const float* q2  = (const float*)d_in[30];
  const float* pW  = (const float*)d_in[31]; const float* pb  = (const float*)d_in[32];

  // ---------------- workspace layout (fp32) ----------------
  float* ws = (float*)d_ws;
  const size_t NB = (size_t)NCn * HIDn;           // 6,400,000 floats per node buffer
  float* B0 = ws;
  float* B1 = ws + NB;
  float* B2 = ws + 2 * NB;
  float* B3 = ws + 3 * NB;
  float* B4 = ws + 4 * NB;
  float* sml = ws + 5 * NB;
  // six dot arrays (N*4 each)
  float* scc = sml;
  float* dcc = sml + 200000;
  float* ddc = sml + 400000;
  float* scd = sml + 600000;
  float* sdc = sml + 800000;
  float* dcd = sml + 1000000;
  float* scoreB = sml + 1200000;                 // [s0,s1,w0,w1, s0',s1',w0',w1']
  float* R0 = sml + 1200016;                     // CSR region (or fallback temps)
  // CSR sub-layout (ints): offs 3x50004 | elist 3x(2*En) | tmp 3x50000
  int*  R0i = (int*)R0;
  int*  offsBase  = R0i;                         // 150,012 ints
  int2* elistBase = (int2*)(R0i + 150012);       // 3*En int2 = 2,400,000 ints
  int*  tmpBase   = R0i + 150012 + 2400000;      // 150,000 ints
  // fallback temps overlay
  unsigned* mbuf = (unsigned*)R0;                // N*4
  float*    sden = R0 + 200000;                  // N*4
  float*    ebuf = R0 + 400000;                  // E*4

  const size_t REQ_FLOATS = 5 * NB + 1200016 + 2700012;   // 35,900,028
  const bool useCsr = ws_size >= REQ_FLOATS * sizeof(float);

  if (useCsr) {
    hipMemsetAsync(tmpBase, 0, 150000 * sizeof(int), stream);
    hist3<<<(3 * En + 255) / 256, 256, 0, stream>>>(ei_cc, ei_dc, ei_cd, tmpBase);
    scan3<<<3, 1024, 0, stream>>>(tmpBase, offsBase);
    hipMemsetAsync(tmpBase, 0, 150000 * sizeof(int), stream);
    fill3<<<(3 * En + 255) / 256, 256, 0, stream>>>(ei_cc, ei_dc, ei_cd,
                                                    offsBase, tmpBase, elistBase);
  }

  hipMemsetAsync(scoreB, 0, 8 * sizeof(float), stream);

  const dim3 gemmGrid((NCn + 63) / 64, HIDn / 64);
  const int NT = (NCn + 63) / 64;
  const int dotGrid = (NCn * 4 + 255) / 256;
  const int* offs0 = offsBase;
  const int* offs1 = offsBase + 50004;
  const int* offs2 = offsBase + 100008;
  const int2* el0 = elistBase;
  const int2* el1 = elistBase + En;
  const int2* el2 = elistBase + 2 * (size_t)En;

  // ---------------- layer 1 ----------------
  gemm_bias<256, 0><<<gemmGrid, 256, 0, stream>>>(xc, nullptr, nullptr, W1c, b1c, B0, NCn, HIDn);
  gemm_bias<256, 0><<<gemmGrid, 256, 0, stream>>>(xd, nullptr, nullptr, W1d, b1d, B1, NDn, HIDn);

  dot6<<<dotGrid, 256, 0, stream>>>(B0, B1, a1s_cc, a1d_cc, a1s_dc, a1d_dc, a1s_cd, a1d_cd,
                                    scc, dcc, ddc, scd, sdc, dcd, NCn);

  if (useCsr) {
    EdgeOp o0{offs0, el0, scc, dcc, B0, B2};
    EdgeOp o1{offs1, el1, sdc, ddc, B1, B3};
    EdgeOp o2{offs2, el2, scd, dcd, B0, B4};
    csr_att3<<<dim3((NCn + 3) / 4, 3), 256, 0, stream>>>(o0, o1, o2, NCn);
  } else {
    run_edge_fb(stream, ei_cc, scc, dcc, B0, B2, NCn, mbuf, sden, ebuf);
    run_edge_fb(stream, ei_dc, sdc, ddc, B1, B3, NCn, mbuf, sden, ebuf);
    run_edge_fb(stream, ei_cd, scd, dcd, B0, B4, NDn, mbuf, sden, ebuf);
  }

  score_gemm<<<dim3(NT, 2, 2), 256, 0, stream>>>(B2, B3, k1W, k1b, q1, NCn, scoreB);
  softmax2_kernel<<<1, 1, 0, stream>>>(scoreB);

  // ---------------- layer 2 (combine/elu fused into A-loads) ----------------
  gemm_bias<128, 2><<<gemmGrid, 256, 0, stream>>>(B2, B3, scoreB, W2c, b2c, B0, NCn, HIDn);
  gemm_bias<128, 1><<<gemmGrid, 256, 0, stream>>>(B4, nullptr, nullptr, W2d, b2d, B1, NDn, HIDn);

  dot6<<<dotGrid, 256, 0, stream>>>(B0, B1, a2s_cc, a2d_cc, a2s_dc, a2d_dc, a2s_cd, a2d_cd,
                                    scc, dcc, ddc, scd, sdc, dcd, NCn);

  if (useCsr) {
    EdgeOp o0{offs0, el0, scc, dcc, B0, B2};
    EdgeOp o1{offs1, el1, sdc, ddc, B1, B3};
    EdgeOp o2{offs2, el2, scd, dcd, B0, B4};
    csr_att3<<<dim3((NCn + 3) / 4, 3), 256, 0, stream>>>(o0, o1, o2, NCn);
  } else {
    run_edge_fb(stream, ei_cc, scc, dcc, B0, B2, NCn, mbuf, sden, ebuf);
    run_edge_fb(stream, ei_dc, sdc, ddc, B1, B3, NCn, mbuf, sden, ebuf);
    run_edge_fb(stream, ei_cd, scd, dcd, B0, B4, NDn, mbuf, sden, ebuf);
  }

  score_gemm<<<dim3(NT, 2, 2), 256, 0, stream>>>(B2, B3, k2W, k2b, q2, NCn, scoreB + 4);
  softmax2_kernel<<<1, 1, 0, stream>>>(scoreB + 4);

  // ---------------- projection (+combine/elu fused) ----------------
  proj_gemm<2, true ><<<NT, 256, 0, stream>>>(B2, B3, scoreB + 4, pW, pb, (float*)d_out, NCn);
  proj_gemm<1, false><<<NT, 256, 0, stream>>>(B4, nullptr, nullptr, pW, pb,
                                              (float*)d_out + (size_t)NCn * OUTn, NDn);
}

// Round 9
// 747.420 us; speedup vs baseline: 4.8073x; 1.0111x over previous
//
#include <hip/hip_runtime.h>
#include <cmath>

#define DEVI static __device__ __forceinline__

constexpr int HIDn = 128, OUTn = 64;
constexpr int NCn = 50000, NDn = 50000, En = 400000;

// monotonic float->uint mapping for atomicMax on floats (handles signs)
DEVI unsigned fmap(float f) {
  int i = __float_as_int(f);
  return (i < 0) ? ~((unsigned)i) : (((unsigned)i) | 0x80000000u);
}
DEVI float fdecode(unsigned u) {
  int i = (u & 0x80000000u) ? (int)(u & 0x7fffffffu) : (int)(~u);
  return __int_as_float(i);
}

DEVI float tanh_fast(float x) {           // 1 - 2/(e^{2x}+1); saturates correctly
  float e = __expf(2.f * x);
  return 1.f - __fdividef(2.f, e + 1.f);
}

// ---- vectorized 8-wide A-row load + fused transform (value-based) -------
// MODE: 0=plain, 1=elu(x), 2=elu(w2*a+w3*b).  base must be 16B-aligned.
template<int MODE>
DEVI void loadrow8(float* __restrict__ tmp,
                   const float* __restrict__ A, const float* __restrict__ A2,
                   float w2, float w3, size_t base)
{
  const float4* p = (const float4*)(A + base);
  float4 u0 = p[0], u1 = p[1];
  float v[8] = {u0.x, u0.y, u0.z, u0.w, u1.x, u1.y, u1.z, u1.w};
  if (MODE == 2) {
    const float4* q = (const float4*)(A2 + base);
    float4 t0 = q[0], t1 = q[1];
    float vb[8] = {t0.x, t0.y, t0.z, t0.w, t1.x, t1.y, t1.z, t1.w};
    #pragma unroll
    for (int i = 0; i < 8; ++i) v[i] = w2 * v[i] + w3 * vb[i];
  }
  if (MODE >= 1) {
    #pragma unroll
    for (int i = 0; i < 8; ++i) v[i] = (v[i] > 0.f) ? v[i] : (__expf(v[i]) - 1.f);
  }
  #pragma unroll
  for (int i = 0; i < 8; ++i) tmp[i] = v[i];
}

// ------- GEMM: C[N,KO] = xform(A)[N,KI] @ W[KI,KO] + b; 128x64 tile ------
// 256 threads, 8x4 acc/thread. grid = (ceil(N/128), KO/64).
template<int KI, int MODE>
__global__ __launch_bounds__(256)
void gemm_bias(const float* __restrict__ A, const float* __restrict__ A2,
               const float* __restrict__ wv,
               const float* __restrict__ W, const float* __restrict__ b,
               float* __restrict__ C, int N, int KO)
{
  __shared__ float At[32][132];   // A^T chunk: [k][row], 128 rows
  __shared__ float Ws[32][68];    // W chunk:   [k][col], 64 cols
  float w2 = 0.f, w3 = 0.f;
  if (MODE == 2) { w2 = wv[2]; w3 = wv[3]; }
  const int row0 = blockIdx.x * 128;
  const int col0 = blockIdx.y * 64;
  const int tid  = threadIdx.x;
  const int r0 = (tid >> 4) << 3;     // 0..120 step 8
  const int c0 = (tid & 15) << 2;     // 0..60  step 4
  float acc[8][4] = {};

  for (int k0 = 0; k0 < KI; k0 += 32) {
    {
      const int r  = tid >> 1;
      const int kq = (tid & 1) << 4;
      const int row = row0 + r;
      float tmp[16];
      if (row < N) {
        loadrow8<MODE>(tmp,     A, A2, w2, w3, (size_t)row * KI + k0 + kq);
        loadrow8<MODE>(tmp + 8, A, A2, w2, w3, (size_t)row * KI + k0 + kq + 8);
      } else {
        #pragma unroll
        for (int i = 0; i < 16; ++i) tmp[i] = 0.f;
      }
      #pragma unroll
      for (int i = 0; i < 16; ++i) At[kq + i][r] = tmp[i];
    }
    {
      const int k  = tid >> 3;
      const int cq = (tid & 7) << 3;
      const float* wp = W + (size_t)(k0 + k) * KO + col0 + cq;
      *(float4*)&Ws[k][cq]     = *(const float4*)wp;
      *(float4*)&Ws[k][cq + 4] = *(const float4*)(wp + 4);
    }
    __syncthreads();
    #pragma unroll
    for (int k = 0; k < 32; ++k) {
      float4 a0v = *(const float4*)&At[k][r0];
      float4 a1v = *(const float4*)&At[k][r0 + 4];
      float4 wv4 = *(const float4*)&Ws[k][c0];
      float av[8] = {a0v.x, a0v.y, a0v.z, a0v.w, a1v.x, a1v.y, a1v.z, a1v.w};
      float wq[4] = {wv4.x, wv4.y, wv4.z, wv4.w};
      #pragma unroll
      for (int i = 0; i < 8; ++i) {
        #pragma unroll
        for (int j = 0; j < 4; ++j) acc[i][j] += av[i] * wq[j];
      }
    }
    __syncthreads();
  }

  #pragma unroll
  for (int i = 0; i < 8; ++i) {
    const int row = row0 + r0 + i;
    if (row >= N) continue;
    #pragma unroll
    for (int j = 0; j < 4; ++j) {
      const int col = col0 + c0 + j;
      C[(size_t)row * KO + col] = acc[i][j] + b[col];
    }
  }
}

// ---- all six per-(node,head) attention dots of one layer in one pass ----
DEVI float dot4f(float4 a, float4 b) { return a.x*b.x + a.y*b.y + a.z*b.z + a.w*b.w; }

__global__ void dot6(const float* __restrict__ hc, const float* __restrict__ hd,
                     const float* __restrict__ ascc, const float* __restrict__ adcc,
                     const float* __restrict__ asdc, const float* __restrict__ addc,
                     const float* __restrict__ ascd, const float* __restrict__ adcd,
                     float* __restrict__ scc, float* __restrict__ dcc,
                     float* __restrict__ ddc, float* __restrict__ scd,
                     float* __restrict__ sdc, float* __restrict__ dcd, int N)
{
  int idx = blockIdx.x * blockDim.x + threadIdx.x;
  if (idx >= N * 4) return;
  int n = idx >> 2, hh = idx & 3;
  const float4* hp = (const float4*)(hc + (size_t)n * HIDn + hh * 32);
  const float4* dp = (const float4*)(hd + (size_t)n * HIDn + hh * 32);
  const float4* a1 = (const float4*)(ascc + hh * 32);
  const float4* a2 = (const float4*)(adcc + hh * 32);
  const float4* a3 = (const float4*)(addc + hh * 32);
  const float4* a4 = (const float4*)(ascd + hh * 32);
  const float4* a5 = (const float4*)(asdc + hh * 32);
  const float4* a6 = (const float4*)(adcd + hh * 32);
  float s1 = 0, s2 = 0, s3 = 0, s4 = 0, t1 = 0, t2 = 0;
  #pragma unroll
  for (int i = 0; i < 8; ++i) {
    float4 hv = hp[i];
    s1 += dot4f(hv, a1[i]);
    s2 += dot4f(hv, a2[i]);
    s3 += dot4f(hv, a3[i]);
    s4 += dot4f(hv, a4[i]);
    float4 dv = dp[i];
    t1 += dot4f(dv, a5[i]);
    t2 += dot4f(dv, a6[i]);
  }
  scc[idx] = s1; dcc[idx] = s2; ddc[idx] = s3;
  scd[idx] = s4; sdc[idx] = t1; dcd[idx] = t2;
}

// ================= CSR build, all 3 graphs batched =======================
__global__ void hist3(const int* __restrict__ ei0, const int* __restrict__ ei1,
                      const int* __restrict__ ei2, int* __restrict__ tmpBase)
{
  int gid = blockIdx.x * blockDim.x + threadIdx.x;
  if (gid >= 3 * En) return;
  int g = gid / En, e = gid - g * En;
  const int* ei = (g == 0) ? ei0 : (g == 1) ? ei1 : ei2;
  atomicAdd(&tmpBase[g * 50000 + ei[En + e]], 1);
}

// one block per graph (grid=3, block=1024)
__global__ void scan3(const int* __restrict__ tmpBase, int* __restrict__ offsBase)
{
  const int n = 50000;
  const int* deg = tmpBase + blockIdx.x * 50000;
  int* offs = offsBase + blockIdx.x * 50004;
  __shared__ int wsum[16];
  __shared__ int carry_sh;
  int tid = threadIdx.x;
  if (tid == 0) { carry_sh = 0; offs[0] = 0; }
  __syncthreads();
  const int nw = blockDim.x >> 6;
  int lane = tid & 63, w = tid >> 6;
  for (int base = 0; base < n; base += blockDim.x) {
    int i = base + tid;
    int v = (i < n) ? deg[i] : 0;
    int x = v;
    #pragma unroll
    for (int off = 1; off < 64; off <<= 1) {
      int y = __shfl_up(x, off);
      if (lane >= off) x += y;
    }
    if (lane == 63) wsum[w] = x;
    __syncthreads();
    if (tid == 0) {
      int s = carry_sh;
      for (int ww = 0; ww < nw; ++ww) { int t = wsum[ww]; wsum[ww] = s; s += t; }
      carry_sh = s;
    }
    __syncthreads();
    if (i < n) offs[i + 1] = wsum[w] + x;
    __syncthreads();
  }
}

__global__ void fill3(const int* __restrict__ ei0, const int* __restrict__ ei1,
                      const int* __restrict__ ei2, const int* __restrict__ offsBase,
                      int* __restrict__ cursorBase, int* __restrict__ elistBase)
{
  int gid = blockIdx.x * blockDim.x + threadIdx.x;
  if (gid >= 3 * En) return;
  int g = gid / En, e = gid - g * En;
  const int* ei = (g == 0) ? ei0 : (g == 1) ? ei1 : ei2;
  const int* offs = offsBase + g * 50004;
  int* cursor = cursorBase + g * 50000;
  int* elist = elistBase + (size_t)g * En;
  int s = ei[e], d = ei[En + e];
  int p = atomicAdd(&cursor[d], 1);
  elist[offs[d] + p] = s;
}

// ==== FUSED edge attention (CSR): single pass, shift-invariant softmax ===
// out[dst] = relu( (Σ_e e^{l_e} h_src[e]) / (Σ_e e^{l_e} + 1e-16) )
// Each of the 16 lanes sharing a head accumulates the identical full den.
struct EdgeOp {
  const int* offs; const int* elist;
  const float* sdot; const float* ddot;
  const float* hsrc; float* out;
};

DEVI void csr_att_body(const EdgeOp& op, int dst, int lane)
{
  const int i0 = op.offs[dst], i1 = op.offs[dst + 1];
  const int hB = lane >> 4;
  const float ddB = op.ddot[dst * 4 + hB];
  const float* hsrc = op.hsrc;
  const float* sdot = op.sdot;
  const int* el = op.elist;
  float den = 0.f, a0 = 0.f, a1 = 0.f;
  int i = i0;
  for (; i + 4 <= i1; i += 4) {
    int s0 = el[i], s1 = el[i + 1], s2 = el[i + 2], s3 = el[i + 3];
    float2 h0 = *(const float2*)(hsrc + (size_t)s0 * HIDn + lane * 2);
    float2 h1 = *(const float2*)(hsrc + (size_t)s1 * HIDn + lane * 2);
    float2 h2 = *(const float2*)(hsrc + (size_t)s2 * HIDn + lane * 2);
    float2 h3 = *(const float2*)(hsrc + (size_t)s3 * HIDn + lane * 2);
    float l0 = sdot[s0 * 4 + hB] + ddB; l0 = fminf(fmaxf(l0, 0.2f * l0), 80.f);
    float l1 = sdot[s1 * 4 + hB] + ddB; l1 = fminf(fmaxf(l1, 0.2f * l1), 80.f);
    float l2 = sdot[s2 * 4 + hB] + ddB; l2 = fminf(fmaxf(l2, 0.2f * l2), 80.f);
    float l3 = sdot[s3 * 4 + hB] + ddB; l3 = fminf(fmaxf(l3, 0.2f * l3), 80.f);
    float e0 = __expf(l0), e1 = __expf(l1), e2 = __expf(l2), e3 = __expf(l3);
    den += (e0 + e1) + (e2 + e3);
    a0 += h0.x * e0 + h1.x * e1 + h2.x * e2 + h3.x * e3;
    a1 += h0.y * e0 + h1.y * e1 + h2.y * e2 + h3.y * e3;
  }
  for (; i < i1; ++i) {
    int s = el[i];
    float2 hv = *(const float2*)(hsrc + (size_t)s * HIDn + lane * 2);
    float lv = sdot[s * 4 + hB] + ddB; lv = fminf(fmaxf(lv, 0.2f * lv), 80.f);
    float e = __expf(lv);
    den += e;
    a0 += hv.x * e;
    a1 += hv.y * e;
  }
  float dinv = __fdividef(1.f, den + 1e-16f);
  float2 o2;
  o2.x = fmaxf(a0 * dinv, 0.f);
  o2.y = fmaxf(a1 * dinv, 0.f);
  *(float2*)(op.out + (size_t)dst * HIDn + lane * 2) = o2;
}

__global__ __launch_bounds__(256)
void csr_att3(EdgeOp op0, EdgeOp op1, EdgeOp op2, int Ndst)
{
  int wave = (blockIdx.x * 256 + threadIdx.x) >> 6;
  if (wave >= Ndst) return;
  const int lane = threadIdx.x & 63;
  if (blockIdx.y == 0)      csr_att_body(op0, wave, lane);
  else if (blockIdx.y == 1) csr_att_body(op1, wave, lane);
  else                      csr_att_body(op2, wave, lane);
}

// ---- fallback path (atomic scatter), used only if ws too small ----------
__global__ void edge_logit_max(const int* __restrict__ ei,
                               const float* __restrict__ sdot,
                               const float* __restrict__ ddot,
                               unsigned* __restrict__ m)
{
  int e = blockIdx.x * blockDim.x + threadIdx.x;
  if (e >= En) return;
  int s = ei[e], d = ei[En + e];
  #pragma unroll
  for (int hh = 0; hh < 4; ++hh) {
    float l = sdot[s * 4 + hh] + ddot[d * 4 + hh];
    l = (l > 0.f) ? l : 0.2f * l;
    atomicMax(&m[d * 4 + hh], fmap(l));
  }
}

__global__ void edge_exp_sum(const int* __restrict__ ei,
                             const float* __restrict__ sdot,
                             const float* __restrict__ ddot,
                             const unsigned* __restrict__ m,
                             float* __restrict__ sden,
                             float* __restrict__ ebuf)
{
  int e = blockIdx.x * blockDim.x + threadIdx.x;
  if (e >= En) return;
  int s = ei[e], d = ei[En + e];
  #pragma unroll
  for (int hh = 0; hh < 4; ++hh) {
    float l = sdot[s * 4 + hh] + ddot[d * 4 + hh];
    l = (l > 0.f) ? l : 0.2f * l;
    float ex = expf(fminf(l - fdecode(m[d * 4 + hh]), 0.f));
    ebuf[e * 4 + hh] = ex;
    atomicAdd(&sden[d * 4 + hh], ex);
  }
}

__global__ __launch_bounds__(256)
void edge_scatter(const int* __restrict__ ei, const float* __restrict__ hsrc,
                  const float* __restrict__ ebuf, const float* __restrict__ sden,
                  float* __restrict__ out)
{
  int gid  = blockIdx.x * 256 + threadIdx.x;
  int e    = gid >> 6;
  if (e >= En) return;
  int lane = gid & 63;
  int s = ei[e], d = ei[En + e];
  #pragma unroll
  for (int half = 0; half < 2; ++half) {
    int c  = lane + half * 64;
    int hh = c >> 5;
    float alpha = ebuf[e * 4 + hh] / (sden[d * 4 + hh] + 1e-16f);
    atomicAdd(&out[(size_t)d * HIDn + c], hsrc[(size_t)s * HIDn + c] * alpha);
  }
}

__global__ void relu_k(float* __restrict__ x, int n)
{
  int i = blockIdx.x * blockDim.x + threadIdx.x;
  if (i < n) x[i] = fmaxf(x[i], 0.f);
}

// ---- semantic-attention score, 128x64 tile, 8x4 acc ---------------------
// grid (ceil(N/128), 2 col-halves, 2 inputs)
__global__ __launch_bounds__(256)
void score_gemm(const float* __restrict__ oA, const float* __restrict__ oB,
                const float* __restrict__ kW, const float* __restrict__ kb,
                const float* __restrict__ q, int N, float* __restrict__ slots)
{
  __shared__ float At[32][132];
  __shared__ float Ws[32][68];
  __shared__ float partw[4];
  const float* o = blockIdx.z ? oB : oA;
  const int row0 = blockIdx.x * 128;
  const int col0 = blockIdx.y * 64;
  const int tid  = threadIdx.x;
  const int r0 = (tid >> 4) << 3;
  const int c0 = (tid & 15) << 2;
  float acc[8][4] = {};

  for (int k0 = 0; k0 < 128; k0 += 32) {
    {
      const int r  = tid >> 1;
      const int kq = (tid & 1) << 4;
      const int row = row0 + r;
      float tmp[16];
      if (row < N) {
        loadrow8<0>(tmp,     o, nullptr, 0.f, 0.f, (size_t)row * HIDn + k0 + kq);
        loadrow8<0>(tmp + 8, o, nullptr, 0.f, 0.f, (size_t)row * HIDn + k0 + kq + 8);
      } else {
        #pragma unroll
        for (int i = 0; i < 16; ++i) tmp[i] = 0.f;
      }
      #pragma unroll
      for (int i = 0; i < 16; ++i) At[kq + i][r] = tmp[i];
    }
    {
      const int k  = tid >> 3;
      const int cq = (tid & 7) << 3;
      const float* wp = kW + (size_t)(k0 + k) * HIDn + col0 + cq;
      *(float4*)&Ws[k][cq]     = *(const float4*)wp;
      *(float4*)&Ws[k][cq + 4] = *(const float4*)(wp + 4);
    }
    __syncthreads();
    #pragma unroll
    for (int k = 0; k < 32; ++k) {
      float4 a0v = *(const float4*)&At[k][r0];
      float4 a1v = *(const float4*)&At[k][r0 + 4];
      float4 wv4 = *(const float4*)&Ws[k][c0];
      float av[8] = {a0v.x, a0v.y, a0v.z, a0v.w, a1v.x, a1v.y, a1v.z, a1v.w};
      float wq[4] = {wv4.x, wv4.y, wv4.z, wv4.w};
      #pragma unroll
      for (int i = 0; i < 8; ++i) {
        #pragma unroll
        for (int j = 0; j < 4; ++j) acc[i][j] += av[i] * wq[j];
      }
    }
    __syncthreads();
  }

  float sum = 0.f;
  #pragma unroll
  for (int i = 0; i < 8; ++i) {
    int row = row0 + r0 + i;
    if (row >= N) continue;
    #pragma unroll
    for (int j = 0; j < 4; ++j) {
      int col = col0 + c0 + j;
      sum += q[col] * tanh_fast(acc[i][j] + kb[col]);
    }
  }
  #pragma unroll
  for (int off = 32; off > 0; off >>= 1) sum += __shfl_down(sum, off);
  int wid = tid >> 6, lane = tid & 63;
  if (lane == 0) partw[wid] = sum;
  __syncthreads();
  if (tid == 0)
    atomicAdd(&slots[blockIdx.z],
              (partw[0] + partw[1] + partw[2] + partw[3]) * (1.f / (float)N));
}

__global__ void softmax2_kernel(float* sb)   // sb[0],sb[1] -> weights sb[2],sb[3]
{
  float s0 = sb[0], s1 = sb[1];
  float mx = fmaxf(s0, s1);
  float e0 = expf(s0 - mx), e1 = expf(s1 - mx);
  float inv = 1.f / (e0 + e1);
  sb[2] = e0 * inv;
  sb[3] = e1 * inv;
}

// ---- final projection, 128x64 tile, 8x4 acc, fused transform ------------
template<int MODE, bool NORM>
__global__ __launch_bounds__(256)
void proj_gemm(const float* __restrict__ fa, const float* __restrict__ fb,
               const float* __restrict__ wv,
               const float* __restrict__ pW, const float* __restrict__ pb,
               float* __restrict__ out, int N)
{
  __shared__ float At[32][132];
  __shared__ float Ws[32][68];
  float w2 = 0.f, w3 = 0.f;
  if (MODE == 2) { w2 = wv[2]; w3 = wv[3]; }
  const int row0 = blockIdx.x * 128;
  const int tid  = threadIdx.x;
  const int r0 = (tid >> 4) << 3;
  const int c0 = (tid & 15) << 2;     // 64 cols
  float acc[8][4] = {};

  for (int k0 = 0; k0 < 128; k0 += 32) {
    {
      const int r  = tid >> 1;
      const int kq = (tid & 1) << 4;
      const int row = row0 + r;
      float tmp[16];
      if (row < N) {
        loadrow8<MODE>(tmp,     fa, fb, w2, w3, (size_t)row * HIDn + k0 + kq);
        loadrow8<MODE>(tmp + 8, fa, fb, w2, w3, (size_t)row * HIDn + k0 + kq + 8);
      } else {
        #pragma unroll
        for (int i = 0; i < 16; ++i) tmp[i] = 0.f;
      }
      #pragma unroll
      for (int i = 0; i < 16; ++i) At[kq + i][r] = tmp[i];
    }
    {
      const int k  = tid >> 3;
      const int cq = (tid & 7) << 3;
      const float* wp = pW + (size_t)(k0 + k) * OUTn + cq;
      *(float4*)&Ws[k][cq]     = *(const float4*)wp;
      *(float4*)&Ws[k][cq + 4] = *(const float4*)(wp + 4);
    }
    __syncthreads();
    #pragma unroll
    for (int k = 0; k < 32; ++k) {
      float4 a0v = *(const float4*)&At[k][r0];
      float4 a1v = *(const float4*)&At[k][r0 + 4];
      float4 wv4 = *(const float4*)&Ws[k][c0];
      float av[8] = {a0v.x, a0v.y, a0v.z, a0v.w, a1v.x, a1v.y, a1v.z, a1v.w};
      float wq[4] = {wv4.x, wv4.y, wv4.z, wv4.w};
      #pragma unroll
      for (int i = 0; i < 8; ++i) {
        #pragma unroll
        for (int j = 0; j < 4; ++j) acc[i][j] += av[i] * wq[j];
      }
    }
    __syncthreads();
  }

  float a[8][4];
  #pragma unroll
  for (int i = 0; i < 8; ++i)
    #pragma unroll
    for (int j = 0; j < 4; ++j) a[i][j] = acc[i][j] + pb[c0 + j];

  if (NORM) {
    // row i lives in the 16 lanes sharing tid>>4 (offsets 1..8 stay in group)
    #pragma unroll
    for (int i = 0; i < 8; ++i) {
      float ss = a[i][0]*a[i][0] + a[i][1]*a[i][1] + a[i][2]*a[i][2] + a[i][3]*a[i][3];
      #pragma unroll
      for (int off = 1; off < 16; off <<= 1) ss += __shfl_xor(ss, off);
      float inv = 1.f / fmaxf(sqrtf(ss), 1e-12f);
      #pragma unroll
      for (int j = 0; j < 4; ++j) a[i][j] *= inv;
    }
  }

  #pragma unroll
  for (int i = 0; i < 8; ++i) {
    int row = row0 + r0 + i;
    if (row >= N) continue;
    #pragma unroll
    for (int j = 0; j < 4; ++j)
      out[(size_t)row * OUTn + c0 + j] = a[i][j];
  }
}

// ---- fallback edge-op dispatcher ----------------------------------------
static void run_edge_fb(hipStream_t stream, const int* ei,
                        const float* sdot, const float* ddot, const float* hsrc,
                        float* outb, int Ndst,
                        unsigned* mbuf, float* sden, float* ebuf)
{
  hipMemsetAsync(mbuf, 0, (size_t)Ndst * 4 * sizeof(unsigned), stream);
  edge_logit_max<<<(En + 255) / 256, 256, 0, stream>>>(ei, sdot, ddot, mbuf);
  hipMemsetAsync(sden, 0, (size_t)Ndst * 4 * sizeof(float), stream);
  edge_exp_sum<<<(En + 255) / 256, 256, 0, stream>>>(ei, sdot, ddot, mbuf, sden, ebuf);
  hipMemsetAsync(outb, 0, (size_t)Ndst * HIDn * sizeof(float), stream);
  edge_scatter<<<((size_t)En * 64 + 255) / 256, 256, 0, stream>>>(ei, hsrc, ebuf, sden, outb);
  relu_k<<<((size_t)Ndst * HIDn + 255) / 256, 256, 0, stream>>>(outb, Ndst * HIDn);
}

extern "C" void kernel_launch(void* const* d_in, const int* in_sizes, int n_in,
                              void* d_out, int out_size, void* d_ws, size_t ws_size,
                              hipStream_t stream)
{
  const float* xc    = (const float*)d_in[0];
  const float* xd    = (const float*)d_in[1];
  const int*   ei_cc = (const int*)d_in[2];
  const int*   ei_dc = (const int*)d_in[3];
  const int*   ei_cd = (const int*)d_in[4];
  const float* W1c = (const float*)d_in[5];  const float* b1c = (const float*)d_in[6];
  const float* W1d = (const float*)d_in[7];  const float* b1d = (const float*)d_in[8];
  const float* a1s_cc = (const float*)d_in[9];  const float* a1d_cc = (const float*)d_in[10];
  const float* a1s_dc = (const float*)d_in[11]; const float* a1d_dc = (const float*)d_in[12];
  const float* a1s_cd = (const float*)d_in[13]; const float* a1d_cd = (const float*)d_in[14];
  const float* k1W = (const float*)d_in[15]; const float* k1b = (const float*)d_in[16];
  const float* q1  = (const float*)d_in[17];
  const float* W2c = (const float*)d_in[18]; const float* b2c = (const float*)d_in[19];
  const float* W2d = (const float*)d_in[20]; const float* b2d = (const float*)d_in[21];
  const float* a2s_cc = (const float*)d_in[22]; const float* a2d_cc = (const float*)d_in[23];
  const float* a2s_dc = (const float*)d_in[24]; const float* a2d_dc = (const float*)d_in[25];
  const float* a2s_cd = (const float*)d_in[26]; const float* a2d_cd = (const float*)d_in[27];
  const float* k2W = (const float*)d_in[28]; const float* k2b = (const float*)d_in[29];
  const float* q2  = (const float*)d_in[30];
  const float* pW  = (const float*)d_in[31]; const float* pb  = (const float*)d_in[32];

  // ---------------- workspace layout (fp32) ----------------
  float* ws = (float*)d_ws;
  const size_t NB = (size_t)NCn * HIDn;           // 6,400,000 floats per node buffer
  float* B0 = ws;
  float* B1 = ws + NB;
  float* B2 = ws + 2 * NB;
  float* B3 = ws + 3 * NB;
  float* B4 = ws + 4 * NB;
  float* sml = ws + 5 * NB;
  // six dot arrays (N*4 each)
  float* scc = sml;
  float* dcc = sml + 200000;
  float* ddc = sml + 400000;
  float* scd = sml + 600000;
  float* sdc = sml + 800000;
  float* dcd = sml + 1000000;
  float* scoreB = sml + 1200000;                 // [s0,s1,w0,w1, s0',s1',w0',w1']
  float* R0 = sml + 1200016;                     // CSR region (or fallback temps)
  // CSR sub-layout (ints): offs 3x50004 | elist 3xEn | tmp 3x50000
  int*  R0i = (int*)R0;
  int*  offsBase  = R0i;                         // 150,012 ints
  int*  elistBase = R0i + 150012;                // 1,200,000 ints
  int*  tmpBase   = R0i + 150012 + 1200000;      // 150,000 ints
  // fallback temps overlay
  unsigned* mbuf = (unsigned*)R0;                // N*4
  float*    sden = R0 + 200000;                  // N*4
  float*    ebuf = R0 + 400000;                  // E*4

  const size_t REQ_FLOATS = 5 * NB + 1200016 + 1500012;   // 34,700,028
  const bool useCsr = ws_size >= REQ_FLOATS * sizeof(float);

  if (useCsr) {
    hipMemsetAsync(tmpBase, 0, 150000 * sizeof(int), stream);
    hist3<<<(3 * En + 255) / 256, 256, 0, stream>>>(ei_cc, ei_dc, ei_cd, tmpBase);
    scan3<<<3, 1024, 0, stream>>>(tmpBase, offsBase);
    hipMemsetAsync(tmpBase, 0, 150000 * sizeof(int), stream);
    fill3<<<(3 * En + 255) / 256, 256, 0, stream>>>(ei_cc, ei_dc, ei_cd,
                                                    offsBase, tmpBase, elistBase);
  }

  hipMemsetAsync(scoreB, 0, 8 * sizeof(float), stream);

  const int NT128 = (NCn + 127) / 128;
  const dim3 gemmGrid(NT128, HIDn / 64);
  const int dotGrid = (NCn * 4 + 255) / 256;
  const int* offs0 = offsBase;
  const int* offs1 = offsBase + 50004;
  const int* offs2 = offsBase + 100008;
  const int* el0 = elistBase;
  const int* el1 = elistBase + En;
  const int* el2 = elistBase + 2 * (size_t)En;

  // ---------------- layer 1 ----------------
  gemm_bias<256, 0><<<gemmGrid, 256, 0, stream>>>(xc, nullptr, nullptr, W1c, b1c, B0, NCn, HIDn);
  gemm_bias<256, 0><<<gemmGrid, 256, 0, stream>>>(xd, nullptr, nullptr, W1d, b1d, B1, NDn, HIDn);

  dot6<<<dotGrid, 256, 0, stream>>>(B0, B1, a1s_cc, a1d_cc, a1s_dc, a1d_dc, a1s_cd, a1d_cd,
                                    scc, dcc, ddc, scd, sdc, dcd, NCn);

  if (useCsr) {
    EdgeOp o0{offs0, el0, scc, dcc, B0, B2};
    EdgeOp o1{offs1, el1, sdc, ddc, B1, B3};
    EdgeOp o2{offs2, el2, scd, dcd, B0, B4};
    csr_att3<<<dim3((NCn + 3) / 4, 3), 256, 0, stream>>>(o0, o1, o2, NCn);
  } else {
    run_edge_fb(stream, ei_cc, scc, dcc, B0, B2, NCn, mbuf, sden, ebuf);
    run_edge_fb(stream, ei_dc, sdc, ddc, B1, B3, NCn, mbuf, sden, ebuf);
    run_edge_fb(stream, ei_cd, scd, dcd, B0, B4, NDn, mbuf, sden, ebuf);
  }

  score_gemm<<<dim3(NT128, 2, 2), 256, 0, stream>>>(B2, B3, k1W, k1b, q1, NCn, scoreB);
  softmax2_kernel<<<1, 1, 0, stream>>>(scoreB);

  // ---------------- layer 2 (combine/elu fused into A-loads) ----------------
  gemm_bias<128, 2><<<gemmGrid, 256, 0, stream>>>(B2, B3, scoreB, W2c, b2c, B0, NCn, HIDn);
  gemm_bias<128, 1><<<gemmGrid, 256, 0, stream>>>(B4, nullptr, nullptr, W2d, b2d, B1, NDn, HIDn);

  dot6<<<dotGrid, 256, 0, stream>>>(B0, B1, a2s_cc, a2d_cc, a2s_dc, a2d_dc, a2s_cd, a2d_cd,
                                    scc, dcc, ddc, scd, sdc, dcd, NCn);

  if (useCsr) {
    EdgeOp o0{offs0, el0, scc, dcc, B0, B2};
    EdgeOp o1{offs1, el1, sdc, ddc, B1, B3};
    EdgeOp o2{offs2, el2, scd, dcd, B0, B4};
    csr_att3<<<dim3((NCn + 3) / 4, 3), 256, 0, stream>>>(o0, o1, o2, NCn);
  } else {
    run_edge_fb(stream, ei_cc, scc, dcc, B0, B2, NCn, mbuf, sden, ebuf);
    run_edge_fb(stream, ei_dc, sdc, ddc, B1, B3, NCn, mbuf, sden, ebuf);
    run_edge_fb(stream, ei_cd, scd, dcd, B0, B4, NDn, mbuf, sden, ebuf);
  }

  score_gemm<<<dim3(NT128, 2, 2), 256, 0, stream>>>(B2, B3, k2W, k2b, q2, NCn, scoreB + 4);
  softmax2_kernel<<<1, 1, 0, stream>>>(scoreB + 4);

  // ---------------- projection (+combine/elu fused) ----------------
  proj_gemm<2, true ><<<NT128, 256, 0, stream>>>(B2, B3, scoreB + 4, pW, pb, (float*)d_out, NCn);
  proj_gemm<1, false><<<NT128, 256, 0, stream>>>(B4, nullptr, nullptr, pW, pb,
                                                 (float*)d_out + (size_t)NCn * OUTn, NDn);
}